// Round 5
// baseline (613.474 us; speedup 1.0000x reference)
//
#include <hip/hip_runtime.h>
#include <hip/hip_bf16.h>
#include <hip/hip_fp16.h>

#define NN 50000
#define NE 800000
#define HID 128
#define NG 256
#define NC 10

// fp16 row helpers: 4 halves packed in a uint2 (8 B)
__device__ __forceinline__ float4 h4tof4(uint2 r)
{
    __half2 a = *(__half2*)&r.x;
    __half2 b = *(__half2*)&r.y;
    float2 fa = __half22float2(a);
    float2 fb = __half22float2(b);
    return make_float4(fa.x, fa.y, fb.x, fb.y);
}

__device__ __forceinline__ uint2 f4toh4(float4 v)
{
    __half2 a = __floats2half2_rn(v.x, v.y);
    __half2 b = __floats2half2_rn(v.z, v.w);
    uint2 r;
    r.x = *(unsigned int*)&a;
    r.y = *(unsigned int*)&b;
    return r;
}

// ---------------------------------------------------------------------------
// dual GEMM: xlh = fp16(in @ Wl), xr = in @ Wr (f32).
// ---------------------------------------------------------------------------
__global__ __launch_bounds__(512) void k_dual_gemm(
    const float* __restrict__ in, const float* __restrict__ Wl,
    const float* __restrict__ Wr, uint2* __restrict__ xlh,
    float* __restrict__ xr, int n)
{
    __shared__ float xs[64 * 128];
    const int tile = blockIdx.x;
    const int t = threadIdx.x;

    for (int f = t * 4; f < 64 * 128; f += 512 * 4) {
        int node = tile * 64 + (f >> 7);
        float4 v = make_float4(0.f, 0.f, 0.f, 0.f);
        if (node < n) v = *(const float4*)(in + (size_t)tile * 8192 + f);
        *(float4*)(xs + f) = v;
    }
    __syncthreads();

    const int cg = t & 63;
    const int ng = t >> 6;
    const int c0 = cg * 4;
    const bool is_l = (c0 < 128);
    const float* Wp = is_l ? (Wl + c0) : (Wr + (c0 - 128));
    const int co = c0 & 127;
    const float* xrow = xs + ng * 8 * 128;

    float4 acc[8];
#pragma unroll
    for (int i = 0; i < 8; i++) acc[i] = make_float4(0.f, 0.f, 0.f, 0.f);

    for (int k0 = 0; k0 < 128; k0 += 4) {
        float4 w0 = *(const float4*)(Wp + (size_t)(k0 + 0) * 128);
        float4 w1 = *(const float4*)(Wp + (size_t)(k0 + 1) * 128);
        float4 w2 = *(const float4*)(Wp + (size_t)(k0 + 2) * 128);
        float4 w3 = *(const float4*)(Wp + (size_t)(k0 + 3) * 128);
#pragma unroll
        for (int i = 0; i < 8; i++) {
            float4 xv = *(const float4*)(xrow + i * 128 + k0);
            acc[i].x = fmaf(xv.x, w0.x, acc[i].x);
            acc[i].y = fmaf(xv.x, w0.y, acc[i].y);
            acc[i].z = fmaf(xv.x, w0.z, acc[i].z);
            acc[i].w = fmaf(xv.x, w0.w, acc[i].w);
            acc[i].x = fmaf(xv.y, w1.x, acc[i].x);
            acc[i].y = fmaf(xv.y, w1.y, acc[i].y);
            acc[i].z = fmaf(xv.y, w1.z, acc[i].z);
            acc[i].w = fmaf(xv.y, w1.w, acc[i].w);
            acc[i].x = fmaf(xv.z, w2.x, acc[i].x);
            acc[i].y = fmaf(xv.z, w2.y, acc[i].y);
            acc[i].z = fmaf(xv.z, w2.z, acc[i].z);
            acc[i].w = fmaf(xv.z, w2.w, acc[i].w);
            acc[i].x = fmaf(xv.w, w3.x, acc[i].x);
            acc[i].y = fmaf(xv.w, w3.y, acc[i].y);
            acc[i].z = fmaf(xv.w, w3.z, acc[i].z);
            acc[i].w = fmaf(xv.w, w3.w, acc[i].w);
        }
    }

#pragma unroll
    for (int i = 0; i < 8; i++) {
        int node = tile * 64 + ng * 8 + i;
        if (node >= n) continue;
        if (is_l)
            xlh[(size_t)node * 32 + (co >> 2)] = f4toh4(acc[i]);
        else
            *(float4*)(xr + (size_t)node * 128 + co) = acc[i];
    }
}

// ---------------------------------------------------------------------------
// CSR build (dst-sorted), once per call, reused by both layers.
// ---------------------------------------------------------------------------
__global__ __launch_bounds__(256) void k_deg_init(int* __restrict__ deg)
{
    int i = blockIdx.x * 256 + threadIdx.x;
    if (i < NN) deg[i] = 1;  // self-loop
}

__global__ __launch_bounds__(256) void k_hist(
    const int* __restrict__ ei, int* __restrict__ deg)
{
    int e = blockIdx.x * 256 + threadIdx.x;
    if (e < NE) atomicAdd(deg + ei[NE + e], 1);
}

__global__ __launch_bounds__(1024) void k_scan(
    const int* __restrict__ deg, int* __restrict__ rowptr)
{
    __shared__ int ps[1024];
    const int t = threadIdx.x;
    const int CH = 49;
    int lo = t * CH, hi = min(lo + CH, NN);
    int s = 0;
    for (int i = lo; i < hi; i++) s += deg[i];
    ps[t] = s;
    __syncthreads();
    for (int off = 1; off < 1024; off <<= 1) {
        int v = (t >= off) ? ps[t - off] : 0;
        __syncthreads();
        ps[t] += v;
        __syncthreads();
    }
    int base = (t == 0) ? 0 : ps[t - 1];
    for (int i = lo; i < hi; i++) { rowptr[i] = base; base += deg[i]; }
    if (t == 0) rowptr[NN] = NE + NN;
}

__global__ __launch_bounds__(256) void k_fill_self(
    const int* __restrict__ rowptr, int* __restrict__ nxt,
    int* __restrict__ esrc)
{
    int i = blockIdx.x * 256 + threadIdx.x;
    if (i >= NN) return;
    int r = rowptr[i];
    esrc[r] = i;
    nxt[i] = r + 1;
}

__global__ __launch_bounds__(256) void k_scatter(
    const int* __restrict__ ei, int* __restrict__ nxt,
    int* __restrict__ esrc)
{
    int e = blockIdx.x * 256 + threadIdx.x;
    if (e >= NE) return;
    int s = ei[e], d = ei[NE + e];
    int pos = atomicAdd(nxt + d, 1);
    esrc[pos] = s;
}

// ---------------------------------------------------------------------------
// Gather GAT row, dependency-free gathers:
//  - lane q loads esrc[chunk+q]  (one coalesced load per 32 edges)
//  - indices broadcast in-register via __shfl (no memory in the chain)
//  - ALL row gathers of the chunk issued back-to-back (<=32 in flight)
// ---------------------------------------------------------------------------
__device__ __forceinline__ void gat_row(
    const uint2* __restrict__ xlh, const float4 xr4, const float4 at,
    const int* __restrict__ esrc, int beg, int end, int q,
    float4& acc, float& den)
{
    acc = make_float4(0.f, 0.f, 0.f, 0.f);
    den = 0.f;

    for (int cb = beg; cb < end; cb += 32) {
        const int nv = min(end - cb, 32);           // valid edges this chunk
        int sidx = esrc[cb + min(q, nv - 1)];       // lane-parallel, coalesced

        uint2 r00, r01, r02, r03, r10, r11, r12, r13;
        uint2 r20, r21, r22, r23, r30, r31, r32, r33;
        uint2 r40, r41, r42, r43, r50, r51, r52, r53;
        uint2 r60, r61, r62, r63, r70, r71, r72, r73;

#define LD(g, ra, rb, rc, rd)                                              \
        {                                                                  \
            int s0 = __shfl(sidx, (g) * 4 + 0, 32);                        \
            int s1 = __shfl(sidx, (g) * 4 + 1, 32);                        \
            int s2 = __shfl(sidx, (g) * 4 + 2, 32);                        \
            int s3 = __shfl(sidx, (g) * 4 + 3, 32);                        \
            ra = xlh[(size_t)s0 * 32 + q];                                 \
            rb = xlh[(size_t)s1 * 32 + q];                                 \
            rc = xlh[(size_t)s2 * 32 + q];                                 \
            rd = xlh[(size_t)s3 * 32 + q];                                 \
        }
                     LD(0, r00, r01, r02, r03)
        if (nv >  4) LD(1, r10, r11, r12, r13)
        if (nv >  8) LD(2, r20, r21, r22, r23)
        if (nv > 12) LD(3, r30, r31, r32, r33)
        if (nv > 16) LD(4, r40, r41, r42, r43)
        if (nv > 20) LD(5, r50, r51, r52, r53)
        if (nv > 24) LD(6, r60, r61, r62, r63)
        if (nv > 28) LD(7, r70, r71, r72, r73)
#undef LD

#define LOGIT(c, e)                                                        \
        {                                                                  \
            float v0 = c.x + xr4.x; v0 = v0 > 0.f ? v0 : 0.2f * v0;        \
            float v1 = c.y + xr4.y; v1 = v1 > 0.f ? v1 : 0.2f * v1;        \
            float v2 = c.z + xr4.z; v2 = v2 > 0.f ? v2 : 0.2f * v2;        \
            float v3 = c.w + xr4.w; v3 = v3 > 0.f ? v3 : 0.2f * v3;        \
            e = v0 * at.x + v1 * at.y + v2 * at.z + v3 * at.w;             \
        }

#define CG(g, ra, rb, rc, rd)                                              \
        {                                                                  \
            float4 c0 = h4tof4(ra), c1 = h4tof4(rb);                       \
            float4 c2 = h4tof4(rc), c3 = h4tof4(rd);                       \
            float e0, e1, e2, e3;                                          \
            LOGIT(c0, e0) LOGIT(c1, e1) LOGIT(c2, e2) LOGIT(c3, e3)        \
            _Pragma("unroll")                                              \
            for (int off = 16; off; off >>= 1) {                           \
                e0 += __shfl_xor(e0, off, 64);                             \
                e1 += __shfl_xor(e1, off, 64);                             \
                e2 += __shfl_xor(e2, off, 64);                             \
                e3 += __shfl_xor(e3, off, 64);                             \
            }                                                              \
            int rem = nv - (g) * 4;                                        \
            float p0 = __expf(fminf(e0, 80.f));                            \
            float p1 = (rem > 1) ? __expf(fminf(e1, 80.f)) : 0.f;          \
            float p2 = (rem > 2) ? __expf(fminf(e2, 80.f)) : 0.f;          \
            float p3 = (rem > 3) ? __expf(fminf(e3, 80.f)) : 0.f;          \
            den += (p0 + p1) + (p2 + p3);                                  \
            acc.x = fmaf(p0, c0.x, fmaf(p1, c1.x, fmaf(p2, c2.x, fmaf(p3, c3.x, acc.x)))); \
            acc.y = fmaf(p0, c0.y, fmaf(p1, c1.y, fmaf(p2, c2.y, fmaf(p3, c3.y, acc.y)))); \
            acc.z = fmaf(p0, c0.z, fmaf(p1, c1.z, fmaf(p2, c2.z, fmaf(p3, c3.z, acc.z)))); \
            acc.w = fmaf(p0, c0.w, fmaf(p1, c1.w, fmaf(p2, c2.w, fmaf(p3, c3.w, acc.w)))); \
        }
                     CG(0, r00, r01, r02, r03)
        if (nv >  4) CG(1, r10, r11, r12, r13)
        if (nv >  8) CG(2, r20, r21, r22, r23)
        if (nv > 12) CG(3, r30, r31, r32, r33)
        if (nv > 16) CG(4, r40, r41, r42, r43)
        if (nv > 20) CG(5, r50, r51, r52, r53)
        if (nv > 24) CG(6, r60, r61, r62, r63)
        if (nv > 28) CG(7, r70, r71, r72, r73)
#undef CG
#undef LOGIT
    }
}

// layer1: fused normalize + bias + ReLU + LayerNorm -> h (f32)
__global__ __launch_bounds__(256) void k_gat1(
    const uint2* __restrict__ xlh, const float* __restrict__ xr,
    const float* __restrict__ att, const int* __restrict__ rowptr,
    const int* __restrict__ esrc, const float* __restrict__ bias,
    const float* __restrict__ g_ln, const float* __restrict__ b_ln,
    float* __restrict__ h)
{
    int d = (int)((blockIdx.x * 256 + threadIdx.x) >> 5);
    int q = threadIdx.x & 31;
    if (d >= NN) return;

    float4 xr4 = *(const float4*)(xr + (size_t)d * 128 + q * 4);
    float4 at  = *(const float4*)(att + q * 4);
    float4 acc; float den;
    gat_row(xlh, xr4, at, esrc, rowptr[d], rowptr[d + 1], q, acc, den);

    float inv = 1.f / (den + 1e-16f);
    float4 bb = *(const float4*)(bias + q * 4);
    float x0 = fmaxf(fmaf(acc.x, inv, bb.x), 0.f);
    float x1 = fmaxf(fmaf(acc.y, inv, bb.y), 0.f);
    float x2 = fmaxf(fmaf(acc.z, inv, bb.z), 0.f);
    float x3 = fmaxf(fmaf(acc.w, inv, bb.w), 0.f);

    float s1 = x0 + x1 + x2 + x3;
    float s2 = x0 * x0 + x1 * x1 + x2 * x2 + x3 * x3;
#pragma unroll
    for (int off = 16; off; off >>= 1) {
        s1 += __shfl_xor(s1, off, 64);
        s2 += __shfl_xor(s2, off, 64);
    }
    float mu = s1 * (1.f / 128.f);
    float var = s2 * (1.f / 128.f) - mu * mu;
    float rstd = rsqrtf(var + 1e-5f);

    float4 g  = *(const float4*)(g_ln + q * 4);
    float4 bl = *(const float4*)(b_ln + q * 4);
    float4 o;
    o.x = (x0 - mu) * rstd * g.x + bl.x;
    o.y = (x1 - mu) * rstd * g.y + bl.y;
    o.z = (x2 - mu) * rstd * g.z + bl.z;
    o.w = (x3 - mu) * rstd * g.w + bl.w;
    *(float4*)(h + (size_t)d * 128 + q * 4) = o;
}

// layer2: fused normalize + bias + mean-pool scatter
__global__ __launch_bounds__(256) void k_gat2(
    const uint2* __restrict__ xlh, const float* __restrict__ xr,
    const float* __restrict__ att, const int* __restrict__ rowptr,
    const int* __restrict__ esrc, const float* __restrict__ bias,
    const int* __restrict__ batch, float* __restrict__ pooled,
    float* __restrict__ cnt)
{
    int d = (int)((blockIdx.x * 256 + threadIdx.x) >> 5);
    int q = threadIdx.x & 31;
    if (d >= NN) return;

    float4 xr4 = *(const float4*)(xr + (size_t)d * 128 + q * 4);
    float4 at  = *(const float4*)(att + q * 4);
    float4 acc; float den;
    gat_row(xlh, xr4, at, esrc, rowptr[d], rowptr[d + 1], q, acc, den);

    float inv = 1.f / (den + 1e-16f);
    float4 bb = *(const float4*)(bias + q * 4);
    int g = batch[d];
    float* pp = pooled + (size_t)g * 128 + q * 4;
    atomicAdd(pp + 0, fmaf(acc.x, inv, bb.x));
    atomicAdd(pp + 1, fmaf(acc.y, inv, bb.y));
    atomicAdd(pp + 2, fmaf(acc.z, inv, bb.z));
    atomicAdd(pp + 3, fmaf(acc.w, inv, bb.w));
    if (q == 0) atomicAdd(cnt + g, 1.f);
}

// ---------------------------------------------------------------------------
__global__ __launch_bounds__(256) void k_linear(
    const float* __restrict__ pooled, const float* __restrict__ cnt,
    const float* __restrict__ W, const float* __restrict__ b,
    float* __restrict__ out)
{
    int idx = blockIdx.x * 256 + threadIdx.x;
    if (idx >= NG * NC) return;
    int g = idx / NC, c = idx % NC;
    float invc = 1.f / fmaxf(cnt[g], 1.f);
    float s = 0.f;
    for (int k = 0; k < HID; k++)
        s = fmaf(pooled[(size_t)g * 128 + k], W[(size_t)k * NC + c], s);
    out[idx] = fmaf(s, invc, b[c]);
}

// ---------------------------------------------------------------------------
extern "C" void kernel_launch(void* const* d_in, const int* in_sizes, int n_in,
                              void* d_out, int out_size, void* d_ws, size_t ws_size,
                              hipStream_t stream)
{
    const float* x     = (const float*)d_in[0];
    const int*   ei    = (const int*)d_in[1];
    const int*   batch = (const int*)d_in[2];
    const float* Wl1   = (const float*)d_in[3];
    const float* Wr1   = (const float*)d_in[4];
    const float* att1  = (const float*)d_in[5];
    const float* b1    = (const float*)d_in[6];
    const float* g_ln  = (const float*)d_in[7];
    const float* b_ln  = (const float*)d_in[8];
    const float* Wl2   = (const float*)d_in[9];
    const float* Wr2   = (const float*)d_in[10];
    const float* att2  = (const float*)d_in[11];
    const float* b2    = (const float*)d_in[12];
    const float* Wlin  = (const float*)d_in[13];
    const float* blin  = (const float*)d_in[14];
    float* out = (float*)d_out;

    char* ws = (char*)d_ws;
    uint2* xlh   = (uint2*)ws;                            // 12.8 MB
    float* xr    = (float*)(ws + (size_t)NN * 256);       // 25.6 MB
    float* h     = xr + (size_t)NN * HID;                 // 25.6 MB
    float* pooled = h + (size_t)NN * HID;                 // 128 KB
    float* cnt   = pooled + (size_t)NG * HID;             // 1 KB
    int* deg    = (int*)(cnt + NG);
    int* rowptr = deg + NN;
    int* nxt    = rowptr + NN + 1;
    int* esrc   = nxt + NN;                               // NE+NN

    const int node_blocks = (NN + 255) / 256;
    const int edge_blocks = (NE + 255) / 256;
    const int gemm_blocks = (NN + 63) / 64;
    const int gat_blocks  = (NN * 32 + 255) / 256;

    // ---- CSR build ----
    k_deg_init<<<node_blocks, 256, 0, stream>>>(deg);
    k_hist<<<edge_blocks, 256, 0, stream>>>(ei, deg);
    k_scan<<<1, 1024, 0, stream>>>(deg, rowptr);
    k_fill_self<<<node_blocks, 256, 0, stream>>>(rowptr, nxt, esrc);
    k_scatter<<<edge_blocks, 256, 0, stream>>>(ei, nxt, esrc);

    hipMemsetAsync(pooled, 0, ((size_t)NG * HID + NG) * sizeof(float), stream);

    // ---- layer 1 ----
    k_dual_gemm<<<gemm_blocks, 512, 0, stream>>>(x, Wl1, Wr1, xlh, xr, NN);
    k_gat1<<<gat_blocks, 256, 0, stream>>>(xlh, xr, att1, rowptr, esrc,
                                           b1, g_ln, b_ln, h);

    // ---- layer 2 ----
    k_dual_gemm<<<gemm_blocks, 512, 0, stream>>>(h, Wl2, Wr2, xlh, xr, NN);
    k_gat2<<<gat_blocks, 256, 0, stream>>>(xlh, xr, att2, rowptr, esrc,
                                           b2, batch, pooled, cnt);

    // ---- head ----
    k_linear<<<(NG * NC + 255) / 256, 256, 0, stream>>>(pooled, cnt, Wlin, blin, out);
}

// Round 6
// 512.882 us; speedup vs baseline: 1.1961x; 1.1961x over previous
//
#include <hip/hip_runtime.h>
#include <hip/hip_bf16.h>
#include <hip/hip_fp16.h>

#define NN 50000
#define NE 800000
#define HID 128
#define NG 256
#define NC 10

__device__ __forceinline__ uint2 f4toh4(float4 v)
{
    __half2 a = __floats2half2_rn(v.x, v.y);
    __half2 b = __floats2half2_rn(v.z, v.w);
    uint2 r;
    r.x = *(unsigned int*)&a;
    r.y = *(unsigned int*)&b;
    return r;
}

// ---------------------------------------------------------------------------
// dual GEMM: xlh = fp16(in @ Wl), xr = in @ Wr (f32).
// ---------------------------------------------------------------------------
__global__ __launch_bounds__(512) void k_dual_gemm(
    const float* __restrict__ in, const float* __restrict__ Wl,
    const float* __restrict__ Wr, uint2* __restrict__ xlh,
    float* __restrict__ xr, int n)
{
    __shared__ float xs[64 * 128];
    const int tile = blockIdx.x;
    const int t = threadIdx.x;

    for (int f = t * 4; f < 64 * 128; f += 512 * 4) {
        int node = tile * 64 + (f >> 7);
        float4 v = make_float4(0.f, 0.f, 0.f, 0.f);
        if (node < n) v = *(const float4*)(in + (size_t)tile * 8192 + f);
        *(float4*)(xs + f) = v;
    }
    __syncthreads();

    const int cg = t & 63;
    const int ng = t >> 6;
    const int c0 = cg * 4;
    const bool is_l = (c0 < 128);
    const float* Wp = is_l ? (Wl + c0) : (Wr + (c0 - 128));
    const int co = c0 & 127;
    const float* xrow = xs + ng * 8 * 128;

    float4 acc[8];
#pragma unroll
    for (int i = 0; i < 8; i++) acc[i] = make_float4(0.f, 0.f, 0.f, 0.f);

    for (int k0 = 0; k0 < 128; k0 += 4) {
        float4 w0 = *(const float4*)(Wp + (size_t)(k0 + 0) * 128);
        float4 w1 = *(const float4*)(Wp + (size_t)(k0 + 1) * 128);
        float4 w2 = *(const float4*)(Wp + (size_t)(k0 + 2) * 128);
        float4 w3 = *(const float4*)(Wp + (size_t)(k0 + 3) * 128);
#pragma unroll
        for (int i = 0; i < 8; i++) {
            float4 xv = *(const float4*)(xrow + i * 128 + k0);
            acc[i].x = fmaf(xv.x, w0.x, acc[i].x);
            acc[i].y = fmaf(xv.x, w0.y, acc[i].y);
            acc[i].z = fmaf(xv.x, w0.z, acc[i].z);
            acc[i].w = fmaf(xv.x, w0.w, acc[i].w);
            acc[i].x = fmaf(xv.y, w1.x, acc[i].x);
            acc[i].y = fmaf(xv.y, w1.y, acc[i].y);
            acc[i].z = fmaf(xv.y, w1.z, acc[i].z);
            acc[i].w = fmaf(xv.y, w1.w, acc[i].w);
            acc[i].x = fmaf(xv.z, w2.x, acc[i].x);
            acc[i].y = fmaf(xv.z, w2.y, acc[i].y);
            acc[i].z = fmaf(xv.z, w2.z, acc[i].z);
            acc[i].w = fmaf(xv.z, w2.w, acc[i].w);
            acc[i].x = fmaf(xv.w, w3.x, acc[i].x);
            acc[i].y = fmaf(xv.w, w3.y, acc[i].y);
            acc[i].z = fmaf(xv.w, w3.z, acc[i].z);
            acc[i].w = fmaf(xv.w, w3.w, acc[i].w);
        }
    }

#pragma unroll
    for (int i = 0; i < 8; i++) {
        int node = tile * 64 + ng * 8 + i;
        if (node >= n) continue;
        if (is_l)
            xlh[(size_t)node * 32 + (co >> 2)] = f4toh4(acc[i]);
        else
            *(float4*)(xr + (size_t)node * 128 + co) = acc[i];
    }
}

// ---------------------------------------------------------------------------
// CSR build (dst-sorted), once per call, reused by both layers.
// ---------------------------------------------------------------------------
__global__ __launch_bounds__(256) void k_deg_init(int* __restrict__ deg)
{
    int i = blockIdx.x * 256 + threadIdx.x;
    if (i < NN) deg[i] = 1;  // self-loop
}

__global__ __launch_bounds__(256) void k_hist(
    const int* __restrict__ ei, int* __restrict__ deg)
{
    int e = blockIdx.x * 256 + threadIdx.x;
    if (e < NE) atomicAdd(deg + ei[NE + e], 1);
}

__global__ __launch_bounds__(1024) void k_scan(
    const int* __restrict__ deg, int* __restrict__ rowptr)
{
    __shared__ int ps[1024];
    const int t = threadIdx.x;
    const int CH = 49;
    int lo = t * CH, hi = min(lo + CH, NN);
    int s = 0;
    for (int i = lo; i < hi; i++) s += deg[i];
    ps[t] = s;
    __syncthreads();
    for (int off = 1; off < 1024; off <<= 1) {
        int v = (t >= off) ? ps[t - off] : 0;
        __syncthreads();
        ps[t] += v;
        __syncthreads();
    }
    int base = (t == 0) ? 0 : ps[t - 1];
    for (int i = lo; i < hi; i++) { rowptr[i] = base; base += deg[i]; }
    if (t == 0) rowptr[NN] = NE + NN;
}

__global__ __launch_bounds__(256) void k_fill_self(
    const int* __restrict__ rowptr, int* __restrict__ nxt,
    int* __restrict__ esrc)
{
    int i = blockIdx.x * 256 + threadIdx.x;
    if (i >= NN) return;
    int r = rowptr[i];
    esrc[r] = i;
    nxt[i] = r + 1;
}

__global__ __launch_bounds__(256) void k_scatter(
    const int* __restrict__ ei, int* __restrict__ nxt,
    int* __restrict__ esrc)
{
    int e = blockIdx.x * 256 + threadIdx.x;
    if (e >= NE) return;
    int s = ei[e], d = ei[NE + e];
    int pos = atomicAdd(nxt + d, 1);
    esrc[pos] = s;
}

// ---------------------------------------------------------------------------
// GAT row, full wave (64 lanes) per dst node; lane holds 2 features (4 B).
//  - 64 edge indices per coalesced load, broadcast by __shfl (scalar)
//  - 16 row-gathers staged per group, 1 VGPR each -> real MLP
// ---------------------------------------------------------------------------
__device__ __forceinline__ void gat_node(
    const unsigned* __restrict__ xlh32, const float2 xr2, const float2 at,
    const int* __restrict__ esrc, int beg, int end, int lane,
    float2& acc, float& den)
{
    acc = make_float2(0.f, 0.f);
    den = 0.f;

    for (int sc = beg; sc < end; sc += 64) {
        const int nv = min(end - sc, 64);               // uniform
        int myidx = esrc[sc + min(lane, nv - 1)];       // coalesced

        for (int g = 0; g < nv; g += 16) {
            const int m = nv - g;                       // valid this group
            unsigned u[16];
#pragma unroll
            for (int k = 0; k < 16; k++) {
                int src = __shfl(myidx, min(g + k, nv - 1), 64);
                u[k] = xlh32[(size_t)src * 64 + lane];
            }
#pragma unroll
            for (int k = 0; k < 16; k++) {
                float2 xl2 = __half22float2(*(__half2*)&u[k]);
                float v0 = xl2.x + xr2.x; v0 = v0 > 0.f ? v0 : 0.2f * v0;
                float v1 = xl2.y + xr2.y; v1 = v1 > 0.f ? v1 : 0.2f * v1;
                float t = v0 * at.x + v1 * at.y;
#pragma unroll
                for (int off = 32; off; off >>= 1) t += __shfl_xor(t, off, 64);
                float p = (k < m) ? __expf(fminf(t, 80.f)) : 0.f;
                den += p;
                acc.x = fmaf(p, xl2.x, acc.x);
                acc.y = fmaf(p, xl2.y, acc.y);
            }
        }
    }
}

// layer1: fused normalize + bias + ReLU + LayerNorm -> h (f32)
__global__ __launch_bounds__(256, 6) void k_gat1(
    const unsigned* __restrict__ xlh32, const float* __restrict__ xr,
    const float* __restrict__ att, const int* __restrict__ rowptr,
    const int* __restrict__ esrc, const float* __restrict__ bias,
    const float* __restrict__ g_ln, const float* __restrict__ b_ln,
    float* __restrict__ h)
{
    int d = (int)((blockIdx.x * 256 + threadIdx.x) >> 6);
    int lane = threadIdx.x & 63;
    if (d >= NN) return;

    float2 xr2 = *(const float2*)(xr + (size_t)d * 128 + lane * 2);
    float2 at  = *(const float2*)(att + lane * 2);
    float2 acc; float den;
    gat_node(xlh32, xr2, at, esrc, rowptr[d], rowptr[d + 1], lane, acc, den);

    float inv = 1.f / (den + 1e-16f);
    float2 bb = *(const float2*)(bias + lane * 2);
    float x0 = fmaxf(fmaf(acc.x, inv, bb.x), 0.f);
    float x1 = fmaxf(fmaf(acc.y, inv, bb.y), 0.f);

    float s1 = x0 + x1, s2 = x0 * x0 + x1 * x1;
#pragma unroll
    for (int off = 32; off; off >>= 1) {
        s1 += __shfl_xor(s1, off, 64);
        s2 += __shfl_xor(s2, off, 64);
    }
    float mu = s1 * (1.f / 128.f);
    float var = s2 * (1.f / 128.f) - mu * mu;
    float rstd = rsqrtf(var + 1e-5f);

    float2 g  = *(const float2*)(g_ln + lane * 2);
    float2 bl = *(const float2*)(b_ln + lane * 2);
    float2 o;
    o.x = (x0 - mu) * rstd * g.x + bl.x;
    o.y = (x1 - mu) * rstd * g.y + bl.y;
    *(float2*)(h + (size_t)d * 128 + lane * 2) = o;
}

// layer2: fused normalize + bias -> h2 (plain write, no atomics)
__global__ __launch_bounds__(256, 6) void k_gat2(
    const unsigned* __restrict__ xlh32, const float* __restrict__ xr,
    const float* __restrict__ att, const int* __restrict__ rowptr,
    const int* __restrict__ esrc, const float* __restrict__ bias,
    float* __restrict__ h2)
{
    int d = (int)((blockIdx.x * 256 + threadIdx.x) >> 6);
    int lane = threadIdx.x & 63;
    if (d >= NN) return;

    float2 xr2 = *(const float2*)(xr + (size_t)d * 128 + lane * 2);
    float2 at  = *(const float2*)(att + lane * 2);
    float2 acc; float den;
    gat_node(xlh32, xr2, at, esrc, rowptr[d], rowptr[d + 1], lane, acc, den);

    float inv = 1.f / (den + 1e-16f);
    float2 bb = *(const float2*)(bias + lane * 2);
    float2 o;
    o.x = fmaf(acc.x, inv, bb.x);
    o.y = fmaf(acc.y, inv, bb.y);
    *(float2*)(h2 + (size_t)d * 128 + lane * 2) = o;
}

// ---------------------------------------------------------------------------
// mean-pool: batch is SORTED -> each block scans a contiguous node range,
// accumulates locally, flushes once per graph boundary via atomics.
// 128 threads, thread = one feature.
// ---------------------------------------------------------------------------
#define NPB 100
__global__ __launch_bounds__(128) void k_pool(
    const float* __restrict__ h2, const int* __restrict__ batch,
    float* __restrict__ pooled, float* __restrict__ cnt)
{
    int n0 = blockIdx.x * NPB;
    int n1 = min(n0 + NPB, NN);
    if (n0 >= NN) return;
    int f = threadIdx.x;

    float s = 0.f;
    int c = 0;
    int curg = batch[n0];
    for (int n = n0; n < n1; n++) {
        int g = batch[n];
        if (g != curg) {
            atomicAdd(pooled + (size_t)curg * 128 + f, s);
            if (f == 0) atomicAdd(cnt + curg, (float)c);
            s = 0.f; c = 0; curg = g;
        }
        s += h2[(size_t)n * 128 + f];
        c++;
    }
    atomicAdd(pooled + (size_t)curg * 128 + f, s);
    if (f == 0) atomicAdd(cnt + curg, (float)c);
}

// ---------------------------------------------------------------------------
__global__ __launch_bounds__(256) void k_linear(
    const float* __restrict__ pooled, const float* __restrict__ cnt,
    const float* __restrict__ W, const float* __restrict__ b,
    float* __restrict__ out)
{
    int idx = blockIdx.x * 256 + threadIdx.x;
    if (idx >= NG * NC) return;
    int g = idx / NC, c = idx % NC;
    float invc = 1.f / fmaxf(cnt[g], 1.f);
    float s = 0.f;
    for (int k = 0; k < HID; k++)
        s = fmaf(pooled[(size_t)g * 128 + k], W[(size_t)k * NC + c], s);
    out[idx] = fmaf(s, invc, b[c]);
}

// ---------------------------------------------------------------------------
extern "C" void kernel_launch(void* const* d_in, const int* in_sizes, int n_in,
                              void* d_out, int out_size, void* d_ws, size_t ws_size,
                              hipStream_t stream)
{
    const float* x     = (const float*)d_in[0];
    const int*   ei    = (const int*)d_in[1];
    const int*   batch = (const int*)d_in[2];
    const float* Wl1   = (const float*)d_in[3];
    const float* Wr1   = (const float*)d_in[4];
    const float* att1  = (const float*)d_in[5];
    const float* b1    = (const float*)d_in[6];
    const float* g_ln  = (const float*)d_in[7];
    const float* b_ln  = (const float*)d_in[8];
    const float* Wl2   = (const float*)d_in[9];
    const float* Wr2   = (const float*)d_in[10];
    const float* att2  = (const float*)d_in[11];
    const float* b2    = (const float*)d_in[12];
    const float* Wlin  = (const float*)d_in[13];
    const float* blin  = (const float*)d_in[14];
    float* out = (float*)d_out;

    char* ws = (char*)d_ws;
    uint2* xlh   = (uint2*)ws;                            // 12.8 MB
    unsigned* xlh32 = (unsigned*)ws;                      // same buffer, u32 view
    float* xr    = (float*)(ws + (size_t)NN * 256);       // 25.6 MB
    float* h     = xr + (size_t)NN * HID;                 // 25.6 MB
    float* h2    = h + (size_t)NN * HID;                  // 25.6 MB
    float* pooled = h2 + (size_t)NN * HID;                // 128 KB
    float* cnt   = pooled + (size_t)NG * HID;             // 1 KB
    int* deg    = (int*)(cnt + NG);
    int* rowptr = deg + NN;
    int* nxt    = rowptr + NN + 1;
    int* esrc   = nxt + NN;                               // NE+NN

    const int node_blocks = (NN + 255) / 256;
    const int edge_blocks = (NE + 255) / 256;
    const int gemm_blocks = (NN + 63) / 64;
    const int gat_blocks  = (NN * 64 + 255) / 256;        // full wave per node

    // ---- CSR build ----
    k_deg_init<<<node_blocks, 256, 0, stream>>>(deg);
    k_hist<<<edge_blocks, 256, 0, stream>>>(ei, deg);
    k_scan<<<1, 1024, 0, stream>>>(deg, rowptr);
    k_fill_self<<<node_blocks, 256, 0, stream>>>(rowptr, nxt, esrc);
    k_scatter<<<edge_blocks, 256, 0, stream>>>(ei, nxt, esrc);

    hipMemsetAsync(pooled, 0, ((size_t)NG * HID + NG) * sizeof(float), stream);

    // ---- layer 1 ----
    k_dual_gemm<<<gemm_blocks, 512, 0, stream>>>(x, Wl1, Wr1, xlh, xr, NN);
    k_gat1<<<gat_blocks, 256, 0, stream>>>(xlh32, xr, att1, rowptr, esrc,
                                           b1, g_ln, b_ln, h);

    // ---- layer 2 ----
    k_dual_gemm<<<gemm_blocks, 512, 0, stream>>>(h, Wl2, Wr2, xlh, xr, NN);
    k_gat2<<<gat_blocks, 256, 0, stream>>>(xlh32, xr, att2, rowptr, esrc,
                                           b2, h2);

    // ---- pool + head ----
    k_pool<<<(NN + NPB - 1) / NPB, 128, 0, stream>>>(h2, batch, pooled, cnt);
    k_linear<<<(NG * NC + 255) / 256, 256, 0, stream>>>(pooled, cnt, Wlin, blin, out);
}

// Round 7
// 407.439 us; speedup vs baseline: 1.5057x; 1.2588x over previous
//
#include <hip/hip_runtime.h>
#include <hip/hip_bf16.h>
#include <hip/hip_fp16.h>

#define NN 50000
#define NE 800000
#define HID 128
#define NG 256
#define NC 10

__device__ __forceinline__ uint2 f4toh4(float4 v)
{
    __half2 a = __floats2half2_rn(v.x, v.y);
    __half2 b = __floats2half2_rn(v.z, v.w);
    uint2 r;
    r.x = *(unsigned int*)&a;
    r.y = *(unsigned int*)&b;
    return r;
}

// ---------------------------------------------------------------------------
// dual GEMM: xlh = fp16(in @ Wl), xr = in @ Wr (f32).
// ---------------------------------------------------------------------------
__global__ __launch_bounds__(512) void k_dual_gemm(
    const float* __restrict__ in, const float* __restrict__ Wl,
    const float* __restrict__ Wr, uint2* __restrict__ xlh,
    float* __restrict__ xr, int n)
{
    __shared__ float xs[64 * 128];
    const int tile = blockIdx.x;
    const int t = threadIdx.x;

    for (int f = t * 4; f < 64 * 128; f += 512 * 4) {
        int node = tile * 64 + (f >> 7);
        float4 v = make_float4(0.f, 0.f, 0.f, 0.f);
        if (node < n) v = *(const float4*)(in + (size_t)tile * 8192 + f);
        *(float4*)(xs + f) = v;
    }
    __syncthreads();

    const int cg = t & 63;
    const int ng = t >> 6;
    const int c0 = cg * 4;
    const bool is_l = (c0 < 128);
    const float* Wp = is_l ? (Wl + c0) : (Wr + (c0 - 128));
    const int co = c0 & 127;
    const float* xrow = xs + ng * 8 * 128;

    float4 acc[8];
#pragma unroll
    for (int i = 0; i < 8; i++) acc[i] = make_float4(0.f, 0.f, 0.f, 0.f);

    for (int k0 = 0; k0 < 128; k0 += 4) {
        float4 w0 = *(const float4*)(Wp + (size_t)(k0 + 0) * 128);
        float4 w1 = *(const float4*)(Wp + (size_t)(k0 + 1) * 128);
        float4 w2 = *(const float4*)(Wp + (size_t)(k0 + 2) * 128);
        float4 w3 = *(const float4*)(Wp + (size_t)(k0 + 3) * 128);
#pragma unroll
        for (int i = 0; i < 8; i++) {
            float4 xv = *(const float4*)(xrow + i * 128 + k0);
            acc[i].x = fmaf(xv.x, w0.x, acc[i].x);
            acc[i].y = fmaf(xv.x, w0.y, acc[i].y);
            acc[i].z = fmaf(xv.x, w0.z, acc[i].z);
            acc[i].w = fmaf(xv.x, w0.w, acc[i].w);
            acc[i].x = fmaf(xv.y, w1.x, acc[i].x);
            acc[i].y = fmaf(xv.y, w1.y, acc[i].y);
            acc[i].z = fmaf(xv.y, w1.z, acc[i].z);
            acc[i].w = fmaf(xv.y, w1.w, acc[i].w);
            acc[i].x = fmaf(xv.z, w2.x, acc[i].x);
            acc[i].y = fmaf(xv.z, w2.y, acc[i].y);
            acc[i].z = fmaf(xv.z, w2.z, acc[i].z);
            acc[i].w = fmaf(xv.z, w2.w, acc[i].w);
            acc[i].x = fmaf(xv.w, w3.x, acc[i].x);
            acc[i].y = fmaf(xv.w, w3.y, acc[i].y);
            acc[i].z = fmaf(xv.w, w3.z, acc[i].z);
            acc[i].w = fmaf(xv.w, w3.w, acc[i].w);
        }
    }

#pragma unroll
    for (int i = 0; i < 8; i++) {
        int node = tile * 64 + ng * 8 + i;
        if (node >= n) continue;
        if (is_l)
            xlh[(size_t)node * 32 + (co >> 2)] = f4toh4(acc[i]);
        else
            *(float4*)(xr + (size_t)node * 128 + co) = acc[i];
    }
}

// ---------------------------------------------------------------------------
// CSR build (dst-sorted), once per call, reused by both layers.
// ---------------------------------------------------------------------------
__global__ __launch_bounds__(256) void k_deg_init(int* __restrict__ deg)
{
    int i = blockIdx.x * 256 + threadIdx.x;
    if (i < NN) deg[i] = 1;  // self-loop
}

__global__ __launch_bounds__(256) void k_hist(
    const int* __restrict__ ei, int* __restrict__ deg)
{
    int e = blockIdx.x * 256 + threadIdx.x;
    if (e < NE) atomicAdd(deg + ei[NE + e], 1);
}

__global__ __launch_bounds__(1024) void k_scan(
    const int* __restrict__ deg, int* __restrict__ rowptr)
{
    __shared__ int ps[1024];
    const int t = threadIdx.x;
    const int CH = 49;
    int lo = t * CH, hi = min(lo + CH, NN);
    int s = 0;
    for (int i = lo; i < hi; i++) s += deg[i];
    ps[t] = s;
    __syncthreads();
    for (int off = 1; off < 1024; off <<= 1) {
        int v = (t >= off) ? ps[t - off] : 0;
        __syncthreads();
        ps[t] += v;
        __syncthreads();
    }
    int base = (t == 0) ? 0 : ps[t - 1];
    for (int i = lo; i < hi; i++) { rowptr[i] = base; base += deg[i]; }
    if (t == 0) rowptr[NN] = NE + NN;
}

__global__ __launch_bounds__(256) void k_fill_self(
    const int* __restrict__ rowptr, int* __restrict__ nxt,
    int* __restrict__ esrc)
{
    int i = blockIdx.x * 256 + threadIdx.x;
    if (i >= NN) return;
    int r = rowptr[i];
    esrc[r] = i;
    nxt[i] = r + 1;
}

__global__ __launch_bounds__(256) void k_scatter(
    const int* __restrict__ ei, int* __restrict__ nxt,
    int* __restrict__ esrc)
{
    int e = blockIdx.x * 256 + threadIdx.x;
    if (e >= NE) return;
    int s = ei[e], d = ei[NE + e];
    int pos = atomicAdd(nxt + d, 1);
    esrc[pos] = s;
}

// ---------------------------------------------------------------------------
// GAT core: one wave per dst node; four 16-lane groups, each group = 1 edge
// per step (4 edges per wave instruction). Lane q holds feats q*8..q*8+7
// (one uint4 of fp16). Logit reduce = 4 shfl steps within 16 lanes.
// A/B/C double-buffered row staging, 32-bit byte-offset addressing.
// ---------------------------------------------------------------------------
__device__ __forceinline__ void gat_core(
    const char* __restrict__ xlb, const int* __restrict__ esrc,
    int beg, int end, int lane, const float* xr8, const float* at8,
    float* acc, float& den)
{
    const int g = lane >> 4;
    const unsigned qb = (unsigned)((lane & 15) << 4);  // byte offset in row
#pragma unroll
    for (int i = 0; i < 8; i++) acc[i] = 0.f;
    den = 0.f;

    for (int sc = beg; sc < end; sc += 64) {
        const int nv = min(end - sc, 64);
        const int nit = (nv + 3) >> 2;
        int myidx = esrc[sc + min(lane, nv - 1)];

        auto LD = [&](int j) -> uint4 {
            int t = (j << 2) + g;
            int s = __shfl(myidx, min(t, nv - 1), 64);
            unsigned off = ((unsigned)s << 8) | qb;
            return *(const uint4*)(xlb + off);
        };

        uint4 A = LD(0);
        uint4 B = LD(nit > 1 ? 1 : 0);
        for (int jj = 0; jj < nit; ++jj) {
            uint4 C = LD(min(jj + 2, nit - 1));

            float xl[8];
            float2 f;
            f = __half22float2(*(__half2*)&A.x); xl[0] = f.x; xl[1] = f.y;
            f = __half22float2(*(__half2*)&A.y); xl[2] = f.x; xl[3] = f.y;
            f = __half22float2(*(__half2*)&A.z); xl[4] = f.x; xl[5] = f.y;
            f = __half22float2(*(__half2*)&A.w); xl[6] = f.x; xl[7] = f.y;

            float e = 0.f;
#pragma unroll
            for (int i = 0; i < 8; i++) {
                float t2 = xl[i] + xr8[i];
                float l = fmaxf(t2, 0.2f * t2);   // leaky_relu
                e = fmaf(l, at8[i], e);
            }
#pragma unroll
            for (int off = 8; off; off >>= 1) e += __shfl_xor(e, off, 64);

            int t = (jj << 2) + g;
            float p = (t < nv) ? __expf(fminf(e, 80.f)) : 0.f;
            den += p;
#pragma unroll
            for (int i = 0; i < 8; i++) acc[i] = fmaf(p, xl[i], acc[i]);

            A = B; B = C;
        }
    }

    // cross-group reduce (4 groups -> full node)
#pragma unroll
    for (int off = 16; off < 64; off <<= 1) {
        den += __shfl_xor(den, off, 64);
#pragma unroll
        for (int i = 0; i < 8; i++) acc[i] += __shfl_xor(acc[i], off, 64);
    }
}

// layer1: fused normalize + bias + ReLU + LayerNorm -> h (f32)
__global__ __launch_bounds__(256, 6) void k_gat1(
    const char* __restrict__ xlb, const float* __restrict__ xr,
    const float* __restrict__ att, const int* __restrict__ rowptr,
    const int* __restrict__ esrc, const float* __restrict__ bias,
    const float* __restrict__ g_ln, const float* __restrict__ b_ln,
    float* __restrict__ h)
{
    int d = (int)((blockIdx.x * 256 + threadIdx.x) >> 6);
    int lane = threadIdx.x & 63;
    if (d >= NN) return;
    int q = lane & 15;

    float xr8[8], at8[8];
    {
        float4 a = *(const float4*)(xr + (size_t)d * 128 + q * 8);
        float4 b = *(const float4*)(xr + (size_t)d * 128 + q * 8 + 4);
        xr8[0]=a.x; xr8[1]=a.y; xr8[2]=a.z; xr8[3]=a.w;
        xr8[4]=b.x; xr8[5]=b.y; xr8[6]=b.z; xr8[7]=b.w;
        float4 c = *(const float4*)(att + q * 8);
        float4 e = *(const float4*)(att + q * 8 + 4);
        at8[0]=c.x; at8[1]=c.y; at8[2]=c.z; at8[3]=c.w;
        at8[4]=e.x; at8[5]=e.y; at8[6]=e.z; at8[7]=e.w;
    }

    float acc[8]; float den;
    gat_core(xlb, esrc, rowptr[d], rowptr[d + 1], lane, xr8, at8, acc, den);

    float inv = 1.f / (den + 1e-16f);
    float x[8];
    {
        float4 a = *(const float4*)(bias + q * 8);
        float4 b = *(const float4*)(bias + q * 8 + 4);
        float bb[8] = {a.x,a.y,a.z,a.w,b.x,b.y,b.z,b.w};
#pragma unroll
        for (int i = 0; i < 8; i++) x[i] = fmaxf(fmaf(acc[i], inv, bb[i]), 0.f);
    }

    float s1 = 0.f, s2 = 0.f;
#pragma unroll
    for (int i = 0; i < 8; i++) { s1 += x[i]; s2 += x[i] * x[i]; }
#pragma unroll
    for (int off = 8; off; off >>= 1) {
        s1 += __shfl_xor(s1, off, 64);
        s2 += __shfl_xor(s2, off, 64);
    }
    float mu = s1 * (1.f / 128.f);
    float var = s2 * (1.f / 128.f) - mu * mu;
    float rstd = rsqrtf(var + 1e-5f);

    if (lane < 16) {
        float4 ga = *(const float4*)(g_ln + q * 8);
        float4 gb = *(const float4*)(g_ln + q * 8 + 4);
        float4 ba = *(const float4*)(b_ln + q * 8);
        float4 bb = *(const float4*)(b_ln + q * 8 + 4);
        float4 o0, o1;
        o0.x = (x[0]-mu)*rstd*ga.x + ba.x;
        o0.y = (x[1]-mu)*rstd*ga.y + ba.y;
        o0.z = (x[2]-mu)*rstd*ga.z + ba.z;
        o0.w = (x[3]-mu)*rstd*ga.w + ba.w;
        o1.x = (x[4]-mu)*rstd*gb.x + bb.x;
        o1.y = (x[5]-mu)*rstd*gb.y + bb.y;
        o1.z = (x[6]-mu)*rstd*gb.z + bb.z;
        o1.w = (x[7]-mu)*rstd*gb.w + bb.w;
        *(float4*)(h + (size_t)d * 128 + q * 8)     = o0;
        *(float4*)(h + (size_t)d * 128 + q * 8 + 4) = o1;
    }
}

// layer2: fused normalize + bias -> h2 (plain write)
__global__ __launch_bounds__(256, 6) void k_gat2(
    const char* __restrict__ xlb, const float* __restrict__ xr,
    const float* __restrict__ att, const int* __restrict__ rowptr,
    const int* __restrict__ esrc, const float* __restrict__ bias,
    float* __restrict__ h2)
{
    int d = (int)((blockIdx.x * 256 + threadIdx.x) >> 6);
    int lane = threadIdx.x & 63;
    if (d >= NN) return;
    int q = lane & 15;

    float xr8[8], at8[8];
    {
        float4 a = *(const float4*)(xr + (size_t)d * 128 + q * 8);
        float4 b = *(const float4*)(xr + (size_t)d * 128 + q * 8 + 4);
        xr8[0]=a.x; xr8[1]=a.y; xr8[2]=a.z; xr8[3]=a.w;
        xr8[4]=b.x; xr8[5]=b.y; xr8[6]=b.z; xr8[7]=b.w;
        float4 c = *(const float4*)(att + q * 8);
        float4 e = *(const float4*)(att + q * 8 + 4);
        at8[0]=c.x; at8[1]=c.y; at8[2]=c.z; at8[3]=c.w;
        at8[4]=e.x; at8[5]=e.y; at8[6]=e.z; at8[7]=e.w;
    }

    float acc[8]; float den;
    gat_core(xlb, esrc, rowptr[d], rowptr[d + 1], lane, xr8, at8, acc, den);

    float inv = 1.f / (den + 1e-16f);
    if (lane < 16) {
        float4 a = *(const float4*)(bias + q * 8);
        float4 b = *(const float4*)(bias + q * 8 + 4);
        float4 o0, o1;
        o0.x = fmaf(acc[0], inv, a.x);
        o0.y = fmaf(acc[1], inv, a.y);
        o0.z = fmaf(acc[2], inv, a.z);
        o0.w = fmaf(acc[3], inv, a.w);
        o1.x = fmaf(acc[4], inv, b.x);
        o1.y = fmaf(acc[5], inv, b.y);
        o1.z = fmaf(acc[6], inv, b.z);
        o1.w = fmaf(acc[7], inv, b.w);
        *(float4*)(h2 + (size_t)d * 128 + q * 8)     = o0;
        *(float4*)(h2 + (size_t)d * 128 + q * 8 + 4) = o1;
    }
}

// ---------------------------------------------------------------------------
// mean-pool: batch sorted -> block scans contiguous range, flush per boundary.
// ---------------------------------------------------------------------------
#define NPB 100
__global__ __launch_bounds__(128) void k_pool(
    const float* __restrict__ h2, const int* __restrict__ batch,
    float* __restrict__ pooled, float* __restrict__ cnt)
{
    int n0 = blockIdx.x * NPB;
    int n1 = min(n0 + NPB, NN);
    if (n0 >= NN) return;
    int f = threadIdx.x;

    float s = 0.f;
    int c = 0;
    int curg = batch[n0];
    for (int n = n0; n < n1; n++) {
        int g = batch[n];
        if (g != curg) {
            atomicAdd(pooled + (size_t)curg * 128 + f, s);
            if (f == 0) atomicAdd(cnt + curg, (float)c);
            s = 0.f; c = 0; curg = g;
        }
        s += h2[(size_t)n * 128 + f];
        c++;
    }
    atomicAdd(pooled + (size_t)curg * 128 + f, s);
    if (f == 0) atomicAdd(cnt + curg, (float)c);
}

// ---------------------------------------------------------------------------
__global__ __launch_bounds__(256) void k_linear(
    const float* __restrict__ pooled, const float* __restrict__ cnt,
    const float* __restrict__ W, const float* __restrict__ b,
    float* __restrict__ out)
{
    int idx = blockIdx.x * 256 + threadIdx.x;
    if (idx >= NG * NC) return;
    int g = idx / NC, c = idx % NC;
    float invc = 1.f / fmaxf(cnt[g], 1.f);
    float s = 0.f;
    for (int k = 0; k < HID; k++)
        s = fmaf(pooled[(size_t)g * 128 + k], W[(size_t)k * NC + c], s);
    out[idx] = fmaf(s, invc, b[c]);
}

// ---------------------------------------------------------------------------
extern "C" void kernel_launch(void* const* d_in, const int* in_sizes, int n_in,
                              void* d_out, int out_size, void* d_ws, size_t ws_size,
                              hipStream_t stream)
{
    const float* x     = (const float*)d_in[0];
    const int*   ei    = (const int*)d_in[1];
    const int*   batch = (const int*)d_in[2];
    const float* Wl1   = (const float*)d_in[3];
    const float* Wr1   = (const float*)d_in[4];
    const float* att1  = (const float*)d_in[5];
    const float* b1    = (const float*)d_in[6];
    const float* g_ln  = (const float*)d_in[7];
    const float* b_ln  = (const float*)d_in[8];
    const float* Wl2   = (const float*)d_in[9];
    const float* Wr2   = (const float*)d_in[10];
    const float* att2  = (const float*)d_in[11];
    const float* b2    = (const float*)d_in[12];
    const float* Wlin  = (const float*)d_in[13];
    const float* blin  = (const float*)d_in[14];
    float* out = (float*)d_out;

    char* ws = (char*)d_ws;
    uint2* xlh   = (uint2*)ws;                            // 12.8 MB
    char* xlb    = ws;                                    // byte view
    float* xr    = (float*)(ws + (size_t)NN * 256);       // 25.6 MB
    float* h     = xr + (size_t)NN * HID;                 // 25.6 MB
    float* h2    = h + (size_t)NN * HID;                  // 25.6 MB
    float* pooled = h2 + (size_t)NN * HID;                // 128 KB
    float* cnt   = pooled + (size_t)NG * HID;             // 1 KB
    int* deg    = (int*)(cnt + NG);
    int* rowptr = deg + NN;
    int* nxt    = rowptr + NN + 1;
    int* esrc   = nxt + NN;                               // NE+NN

    const int node_blocks = (NN + 255) / 256;
    const int edge_blocks = (NE + 255) / 256;
    const int gemm_blocks = (NN + 63) / 64;
    const int gat_blocks  = (NN * 64 + 255) / 256;        // wave per node

    // ---- CSR build ----
    k_deg_init<<<node_blocks, 256, 0, stream>>>(deg);
    k_hist<<<edge_blocks, 256, 0, stream>>>(ei, deg);
    k_scan<<<1, 1024, 0, stream>>>(deg, rowptr);
    k_fill_self<<<node_blocks, 256, 0, stream>>>(rowptr, nxt, esrc);
    k_scatter<<<edge_blocks, 256, 0, stream>>>(ei, nxt, esrc);

    hipMemsetAsync(pooled, 0, ((size_t)NG * HID + NG) * sizeof(float), stream);

    // ---- layer 1 ----
    k_dual_gemm<<<gemm_blocks, 512, 0, stream>>>(x, Wl1, Wr1, xlh, xr, NN);
    k_gat1<<<gat_blocks, 256, 0, stream>>>(xlb, xr, att1, rowptr, esrc,
                                           b1, g_ln, b_ln, h);

    // ---- layer 2 ----
    k_dual_gemm<<<gemm_blocks, 512, 0, stream>>>(h, Wl2, Wr2, xlh, xr, NN);
    k_gat2<<<gat_blocks, 256, 0, stream>>>(xlb, xr, att2, rowptr, esrc,
                                           b2, h2);

    // ---- pool + head ----
    k_pool<<<(NN + NPB - 1) / NPB, 128, 0, stream>>>(h2, batch, pooled, cnt);
    k_linear<<<(NG * NC + 255) / 256, 256, 0, stream>>>(pooled, cnt, Wlin, blin, out);
}

// Round 8
// 337.230 us; speedup vs baseline: 1.8192x; 1.2082x over previous
//
#include <hip/hip_runtime.h>
#include <hip/hip_bf16.h>
#include <hip/hip_fp16.h>

#define NN 50000
#define NE 800000
#define HID 128
#define NG 256
#define NC 10
#define NB 196  // (NN + 255) / 256

__device__ __forceinline__ uint2 f4toh4(float4 v)
{
    __half2 a = __floats2half2_rn(v.x, v.y);
    __half2 b = __floats2half2_rn(v.z, v.w);
    uint2 r;
    r.x = *(unsigned int*)&a;
    r.y = *(unsigned int*)&b;
    return r;
}

// ---------------------------------------------------------------------------
// dual GEMM: xlh = fp16(in @ Wl), xr = in @ Wr (f32).
// ---------------------------------------------------------------------------
__global__ __launch_bounds__(512) void k_dual_gemm(
    const float* __restrict__ in, const float* __restrict__ Wl,
    const float* __restrict__ Wr, uint2* __restrict__ xlh,
    float* __restrict__ xr, int n)
{
    __shared__ float xs[64 * 128];
    const int tile = blockIdx.x;
    const int t = threadIdx.x;

    for (int f = t * 4; f < 64 * 128; f += 512 * 4) {
        int node = tile * 64 + (f >> 7);
        float4 v = make_float4(0.f, 0.f, 0.f, 0.f);
        if (node < n) v = *(const float4*)(in + (size_t)tile * 8192 + f);
        *(float4*)(xs + f) = v;
    }
    __syncthreads();

    const int cg = t & 63;
    const int ng = t >> 6;
    const int c0 = cg * 4;
    const bool is_l = (c0 < 128);
    const float* Wp = is_l ? (Wl + c0) : (Wr + (c0 - 128));
    const int co = c0 & 127;
    const float* xrow = xs + ng * 8 * 128;

    float4 acc[8];
#pragma unroll
    for (int i = 0; i < 8; i++) acc[i] = make_float4(0.f, 0.f, 0.f, 0.f);

    for (int k0 = 0; k0 < 128; k0 += 4) {
        float4 w0 = *(const float4*)(Wp + (size_t)(k0 + 0) * 128);
        float4 w1 = *(const float4*)(Wp + (size_t)(k0 + 1) * 128);
        float4 w2 = *(const float4*)(Wp + (size_t)(k0 + 2) * 128);
        float4 w3 = *(const float4*)(Wp + (size_t)(k0 + 3) * 128);
#pragma unroll
        for (int i = 0; i < 8; i++) {
            float4 xv = *(const float4*)(xrow + i * 128 + k0);
            acc[i].x = fmaf(xv.x, w0.x, acc[i].x);
            acc[i].y = fmaf(xv.x, w0.y, acc[i].y);
            acc[i].z = fmaf(xv.x, w0.z, acc[i].z);
            acc[i].w = fmaf(xv.x, w0.w, acc[i].w);
            acc[i].x = fmaf(xv.y, w1.x, acc[i].x);
            acc[i].y = fmaf(xv.y, w1.y, acc[i].y);
            acc[i].z = fmaf(xv.y, w1.z, acc[i].z);
            acc[i].w = fmaf(xv.y, w1.w, acc[i].w);
            acc[i].x = fmaf(xv.z, w2.x, acc[i].x);
            acc[i].y = fmaf(xv.z, w2.y, acc[i].y);
            acc[i].z = fmaf(xv.z, w2.z, acc[i].z);
            acc[i].w = fmaf(xv.z, w2.w, acc[i].w);
            acc[i].x = fmaf(xv.w, w3.x, acc[i].x);
            acc[i].y = fmaf(xv.w, w3.y, acc[i].y);
            acc[i].z = fmaf(xv.w, w3.z, acc[i].z);
            acc[i].w = fmaf(xv.w, w3.w, acc[i].w);
        }
    }

#pragma unroll
    for (int i = 0; i < 8; i++) {
        int node = tile * 64 + ng * 8 + i;
        if (node >= n) continue;
        if (is_l)
            xlh[(size_t)node * 32 + (co >> 2)] = f4toh4(acc[i]);
        else
            *(float4*)(xr + (size_t)node * 128 + co) = acc[i];
    }
}

// ---------------------------------------------------------------------------
// CSR build: hist -> hierarchical scan (3 parallel phases, fill fused).
// Self-loop for node d occupies slot rowptr[d]; real edges follow.
// ---------------------------------------------------------------------------
__global__ __launch_bounds__(256) void k_hist(
    const int* __restrict__ ei, int* __restrict__ deg)
{
    int e = blockIdx.x * 256 + threadIdx.x;
    if (e < NE) atomicAdd(deg + ei[NE + e], 1);
}

__device__ __forceinline__ int block_scan_incl(int v, int t)
{
    __shared__ int sm[256];
    sm[t] = v;
    __syncthreads();
#pragma unroll
    for (int off = 1; off < 256; off <<= 1) {
        int u = (t >= off) ? sm[t - off] : 0;
        __syncthreads();
        sm[t] += u;
        __syncthreads();
    }
    return sm[t];
}

// phase 1: block-local exclusive prefix into rowptr, block total into bsum
__global__ __launch_bounds__(256) void k_scan1(
    const int* __restrict__ deg, int* __restrict__ rowptr,
    int* __restrict__ bsum)
{
    int t = threadIdx.x;
    int i = blockIdx.x * 256 + t;
    int v = (i < NN) ? deg[i] + 1 : 0;  // +1 = self-loop
    int inc = block_scan_incl(v, t);
    if (i < NN) rowptr[i] = inc - v;
    if (t == 255) bsum[blockIdx.x] = inc;
}

// phase 2: scan the 196 block totals (1 block)
__global__ __launch_bounds__(256) void k_scan2(int* __restrict__ bsum)
{
    int t = threadIdx.x;
    int v = (t < NB) ? bsum[t] : 0;
    int inc = block_scan_incl(v, t);
    if (t < NB) bsum[t] = inc - v;  // exclusive
}

// phase 3: add block offset; fuse self-loop fill + nxt init
__global__ __launch_bounds__(256) void k_scan3(
    int* __restrict__ rowptr, const int* __restrict__ bsum,
    int* __restrict__ nxt, int* __restrict__ esrc)
{
    int i = blockIdx.x * 256 + threadIdx.x;
    if (i < NN) {
        int r = rowptr[i] + bsum[blockIdx.x];
        rowptr[i] = r;
        esrc[r] = i;      // self-loop in slot 0 of the row
        nxt[i] = r + 1;
    }
    if (i == 0) rowptr[NN] = NE + NN;
}

__global__ __launch_bounds__(256) void k_scatter(
    const int* __restrict__ ei, int* __restrict__ nxt,
    int* __restrict__ esrc)
{
    int e = blockIdx.x * 256 + threadIdx.x;
    if (e >= NE) return;
    int s = ei[e], d = ei[NE + e];
    int pos = atomicAdd(nxt + d, 1);
    esrc[pos] = s;
}

// ---------------------------------------------------------------------------
// GAT core: one wave per dst node; four 16-lane groups, each group = 1 edge
// per step (4 edges per wave instruction). Lane q holds feats q*8..q*8+7
// (one uint4 of fp16). Logit reduce = 4 shfl steps within 16 lanes.
// ---------------------------------------------------------------------------
__device__ __forceinline__ void gat_core(
    const char* __restrict__ xlb, const int* __restrict__ esrc,
    int beg, int end, int lane, const float* xr8, const float* at8,
    float* acc, float& den)
{
    const int g = lane >> 4;
    const unsigned qb = (unsigned)((lane & 15) << 4);  // byte offset in row
#pragma unroll
    for (int i = 0; i < 8; i++) acc[i] = 0.f;
    den = 0.f;

    for (int sc = beg; sc < end; sc += 64) {
        const int nv = min(end - sc, 64);
        const int nit = (nv + 3) >> 2;
        int myidx = esrc[sc + min(lane, nv - 1)];

        auto LD = [&](int j) -> uint4 {
            int t = (j << 2) + g;
            int s = __shfl(myidx, min(t, nv - 1), 64);
            unsigned off = ((unsigned)s << 8) | qb;
            return *(const uint4*)(xlb + off);
        };

        uint4 A = LD(0);
        uint4 B = LD(nit > 1 ? 1 : 0);
        for (int jj = 0; jj < nit; ++jj) {
            uint4 C = LD(min(jj + 2, nit - 1));

            float xl[8];
            float2 f;
            f = __half22float2(*(__half2*)&A.x); xl[0] = f.x; xl[1] = f.y;
            f = __half22float2(*(__half2*)&A.y); xl[2] = f.x; xl[3] = f.y;
            f = __half22float2(*(__half2*)&A.z); xl[4] = f.x; xl[5] = f.y;
            f = __half22float2(*(__half2*)&A.w); xl[6] = f.x; xl[7] = f.y;

            float e = 0.f;
#pragma unroll
            for (int i = 0; i < 8; i++) {
                float t2 = xl[i] + xr8[i];
                float l = fmaxf(t2, 0.2f * t2);   // leaky_relu
                e = fmaf(l, at8[i], e);
            }
#pragma unroll
            for (int off = 8; off; off >>= 1) e += __shfl_xor(e, off, 64);

            int t = (jj << 2) + g;
            float p = (t < nv) ? __expf(fminf(e, 80.f)) : 0.f;
            den += p;
#pragma unroll
            for (int i = 0; i < 8; i++) acc[i] = fmaf(p, xl[i], acc[i]);

            A = B; B = C;
        }
    }

    // cross-group reduce (4 groups -> full node)
#pragma unroll
    for (int off = 16; off < 64; off <<= 1) {
        den += __shfl_xor(den, off, 64);
#pragma unroll
        for (int i = 0; i < 8; i++) acc[i] += __shfl_xor(acc[i], off, 64);
    }
}

// layer1: fused normalize + bias + ReLU + LayerNorm -> h (f32)
__global__ __launch_bounds__(256, 6) void k_gat1(
    const char* __restrict__ xlb, const float* __restrict__ xr,
    const float* __restrict__ att, const int* __restrict__ rowptr,
    const int* __restrict__ esrc, const float* __restrict__ bias,
    const float* __restrict__ g_ln, const float* __restrict__ b_ln,
    float* __restrict__ h)
{
    int d = (int)((blockIdx.x * 256 + threadIdx.x) >> 6);
    int lane = threadIdx.x & 63;
    if (d >= NN) return;
    int q = lane & 15;

    float xr8[8], at8[8];
    {
        float4 a = *(const float4*)(xr + (size_t)d * 128 + q * 8);
        float4 b = *(const float4*)(xr + (size_t)d * 128 + q * 8 + 4);
        xr8[0]=a.x; xr8[1]=a.y; xr8[2]=a.z; xr8[3]=a.w;
        xr8[4]=b.x; xr8[5]=b.y; xr8[6]=b.z; xr8[7]=b.w;
        float4 c = *(const float4*)(att + q * 8);
        float4 e = *(const float4*)(att + q * 8 + 4);
        at8[0]=c.x; at8[1]=c.y; at8[2]=c.z; at8[3]=c.w;
        at8[4]=e.x; at8[5]=e.y; at8[6]=e.z; at8[7]=e.w;
    }

    float acc[8]; float den;
    gat_core(xlb, esrc, rowptr[d], rowptr[d + 1], lane, xr8, at8, acc, den);

    float inv = 1.f / (den + 1e-16f);
    float x[8];
    {
        float4 a = *(const float4*)(bias + q * 8);
        float4 b = *(const float4*)(bias + q * 8 + 4);
        float bb[8] = {a.x,a.y,a.z,a.w,b.x,b.y,b.z,b.w};
#pragma unroll
        for (int i = 0; i < 8; i++) x[i] = fmaxf(fmaf(acc[i], inv, bb[i]), 0.f);
    }

    float s1 = 0.f, s2 = 0.f;
#pragma unroll
    for (int i = 0; i < 8; i++) { s1 += x[i]; s2 += x[i] * x[i]; }
#pragma unroll
    for (int off = 8; off; off >>= 1) {
        s1 += __shfl_xor(s1, off, 64);
        s2 += __shfl_xor(s2, off, 64);
    }
    float mu = s1 * (1.f / 128.f);
    float var = s2 * (1.f / 128.f) - mu * mu;
    float rstd = rsqrtf(var + 1e-5f);

    if (lane < 16) {
        float4 ga = *(const float4*)(g_ln + q * 8);
        float4 gb = *(const float4*)(g_ln + q * 8 + 4);
        float4 ba = *(const float4*)(b_ln + q * 8);
        float4 bb = *(const float4*)(b_ln + q * 8 + 4);
        float4 o0, o1;
        o0.x = (x[0]-mu)*rstd*ga.x + ba.x;
        o0.y = (x[1]-mu)*rstd*ga.y + ba.y;
        o0.z = (x[2]-mu)*rstd*ga.z + ba.z;
        o0.w = (x[3]-mu)*rstd*ga.w + ba.w;
        o1.x = (x[4]-mu)*rstd*gb.x + bb.x;
        o1.y = (x[5]-mu)*rstd*gb.y + bb.y;
        o1.z = (x[6]-mu)*rstd*gb.z + bb.z;
        o1.w = (x[7]-mu)*rstd*gb.w + bb.w;
        *(float4*)(h + (size_t)d * 128 + q * 8)     = o0;
        *(float4*)(h + (size_t)d * 128 + q * 8 + 4) = o1;
    }
}

// layer2: fused normalize + bias -> h2 (plain write)
__global__ __launch_bounds__(256, 6) void k_gat2(
    const char* __restrict__ xlb, const float* __restrict__ xr,
    const float* __restrict__ att, const int* __restrict__ rowptr,
    const int* __restrict__ esrc, const float* __restrict__ bias,
    float* __restrict__ h2)
{
    int d = (int)((blockIdx.x * 256 + threadIdx.x) >> 6);
    int lane = threadIdx.x & 63;
    if (d >= NN) return;
    int q = lane & 15;

    float xr8[8], at8[8];
    {
        float4 a = *(const float4*)(xr + (size_t)d * 128 + q * 8);
        float4 b = *(const float4*)(xr + (size_t)d * 128 + q * 8 + 4);
        xr8[0]=a.x; xr8[1]=a.y; xr8[2]=a.z; xr8[3]=a.w;
        xr8[4]=b.x; xr8[5]=b.y; xr8[6]=b.z; xr8[7]=b.w;
        float4 c = *(const float4*)(att + q * 8);
        float4 e = *(const float4*)(att + q * 8 + 4);
        at8[0]=c.x; at8[1]=c.y; at8[2]=c.z; at8[3]=c.w;
        at8[4]=e.x; at8[5]=e.y; at8[6]=e.z; at8[7]=e.w;
    }

    float acc[8]; float den;
    gat_core(xlb, esrc, rowptr[d], rowptr[d + 1], lane, xr8, at8, acc, den);

    float inv = 1.f / (den + 1e-16f);
    if (lane < 16) {
        float4 a = *(const float4*)(bias + q * 8);
        float4 b = *(const float4*)(bias + q * 8 + 4);
        float4 o0, o1;
        o0.x = fmaf(acc[0], inv, a.x);
        o0.y = fmaf(acc[1], inv, a.y);
        o0.z = fmaf(acc[2], inv, a.z);
        o0.w = fmaf(acc[3], inv, a.w);
        o1.x = fmaf(acc[4], inv, b.x);
        o1.y = fmaf(acc[5], inv, b.y);
        o1.z = fmaf(acc[6], inv, b.z);
        o1.w = fmaf(acc[7], inv, b.w);
        *(float4*)(h2 + (size_t)d * 128 + q * 8)     = o0;
        *(float4*)(h2 + (size_t)d * 128 + q * 8 + 4) = o1;
    }
}

// ---------------------------------------------------------------------------
// mean-pool: batch sorted -> block scans contiguous range, flush per boundary.
// ---------------------------------------------------------------------------
#define NPB 100
__global__ __launch_bounds__(128) void k_pool(
    const float* __restrict__ h2, const int* __restrict__ batch,
    float* __restrict__ pooled, float* __restrict__ cnt)
{
    int n0 = blockIdx.x * NPB;
    int n1 = min(n0 + NPB, NN);
    if (n0 >= NN) return;
    int f = threadIdx.x;

    float s = 0.f;
    int c = 0;
    int curg = batch[n0];
    for (int n = n0; n < n1; n++) {
        int g = batch[n];
        if (g != curg) {
            atomicAdd(pooled + (size_t)curg * 128 + f, s);
            if (f == 0) atomicAdd(cnt + curg, (float)c);
            s = 0.f; c = 0; curg = g;
        }
        s += h2[(size_t)n * 128 + f];
        c++;
    }
    atomicAdd(pooled + (size_t)curg * 128 + f, s);
    if (f == 0) atomicAdd(cnt + curg, (float)c);
}

// ---------------------------------------------------------------------------
__global__ __launch_bounds__(256) void k_linear(
    const float* __restrict__ pooled, const float* __restrict__ cnt,
    const float* __restrict__ W, const float* __restrict__ b,
    float* __restrict__ out)
{
    int idx = blockIdx.x * 256 + threadIdx.x;
    if (idx >= NG * NC) return;
    int g = idx / NC, c = idx % NC;
    float invc = 1.f / fmaxf(cnt[g], 1.f);
    float s = 0.f;
    for (int k = 0; k < HID; k++)
        s = fmaf(pooled[(size_t)g * 128 + k], W[(size_t)k * NC + c], s);
    out[idx] = fmaf(s, invc, b[c]);
}

// ---------------------------------------------------------------------------
extern "C" void kernel_launch(void* const* d_in, const int* in_sizes, int n_in,
                              void* d_out, int out_size, void* d_ws, size_t ws_size,
                              hipStream_t stream)
{
    const float* x     = (const float*)d_in[0];
    const int*   ei    = (const int*)d_in[1];
    const int*   batch = (const int*)d_in[2];
    const float* Wl1   = (const float*)d_in[3];
    const float* Wr1   = (const float*)d_in[4];
    const float* att1  = (const float*)d_in[5];
    const float* b1    = (const float*)d_in[6];
    const float* g_ln  = (const float*)d_in[7];
    const float* b_ln  = (const float*)d_in[8];
    const float* Wl2   = (const float*)d_in[9];
    const float* Wr2   = (const float*)d_in[10];
    const float* att2  = (const float*)d_in[11];
    const float* b2    = (const float*)d_in[12];
    const float* Wlin  = (const float*)d_in[13];
    const float* blin  = (const float*)d_in[14];
    float* out = (float*)d_out;

    char* ws = (char*)d_ws;
    uint2* xlh   = (uint2*)ws;                            // 12.8 MB
    char* xlb    = ws;                                    // byte view
    float* xr    = (float*)(ws + (size_t)NN * 256);       // 25.6 MB
    float* h     = xr + (size_t)NN * HID;                 // 25.6 MB
    float* h2    = h + (size_t)NN * HID;                  // 25.6 MB
    float* pooled = h2 + (size_t)NN * HID;                // 128 KB
    float* cnt   = pooled + (size_t)NG * HID;             // 1 KB
    int* deg    = (int*)(cnt + NG);                       // NN
    int* rowptr = deg + NN;                               // NN+1
    int* nxt    = rowptr + NN + 1;                        // NN
    int* bsum   = nxt + NN;                               // NB
    int* esrc   = bsum + 256;                             // NE+NN

    const int edge_blocks = (NE + 255) / 256;
    const int gemm_blocks = (NN + 63) / 64;
    const int gat_blocks  = (NN * 64 + 255) / 256;        // wave per node

    // ---- CSR build (hierarchical scan, fill fused into phase 3) ----
    hipMemsetAsync(deg, 0, NN * sizeof(int), stream);
    k_hist<<<edge_blocks, 256, 0, stream>>>(ei, deg);
    k_scan1<<<NB, 256, 0, stream>>>(deg, rowptr, bsum);
    k_scan2<<<1, 256, 0, stream>>>(bsum);
    k_scan3<<<NB, 256, 0, stream>>>(rowptr, bsum, nxt, esrc);
    k_scatter<<<edge_blocks, 256, 0, stream>>>(ei, nxt, esrc);

    hipMemsetAsync(pooled, 0, ((size_t)NG * HID + NG) * sizeof(float), stream);

    // ---- layer 1 ----
    k_dual_gemm<<<gemm_blocks, 512, 0, stream>>>(x, Wl1, Wr1, xlh, xr, NN);
    k_gat1<<<gat_blocks, 256, 0, stream>>>(xlb, xr, att1, rowptr, esrc,
                                           b1, g_ln, b_ln, h);

    // ---- layer 2 ----
    k_dual_gemm<<<gemm_blocks, 512, 0, stream>>>(h, Wl2, Wr2, xlh, xr, NN);
    k_gat2<<<gat_blocks, 256, 0, stream>>>(xlb, xr, att2, rowptr, esrc,
                                           b2, h2);

    // ---- pool + head ----
    k_pool<<<(NN + NPB - 1) / NPB, 128, 0, stream>>>(h2, batch, pooled, cnt);
    k_linear<<<(NG * NC + 255) / 256, 256, 0, stream>>>(pooled, cnt, Wlin, blin, out);
}

// Round 9
// 272.826 us; speedup vs baseline: 2.2486x; 1.2361x over previous
//
#include <hip/hip_runtime.h>
#include <hip/hip_bf16.h>
#include <hip/hip_fp16.h>

#define NN 50000
#define NE 800000
#define HID 128
#define NG 256
#define NC 10
#define NB 196  // (NN + 255) / 256

using half8 = __attribute__((ext_vector_type(8))) _Float16;
using f32x4 = __attribute__((ext_vector_type(4))) float;

// ---------------------------------------------------------------------------
// W pack: [Wl|Wr] f32 [128][128] -> fragment-ready fp16.
// tile t in [0,16) (t<8: Wl cols t*16.., else Wr), kf in [0,4), lane in [0,64):
//   elem j = W[kf*32 + (lane>>4)*8 + j][ (t&7)*16 + (lane&15) ]
// stored at halves offset ((t*4+kf)*64 + lane)*8  (idx*8).
// ---------------------------------------------------------------------------
__global__ __launch_bounds__(256) void k_wpack(
    const float* __restrict__ Wl, const float* __restrict__ Wr,
    __half* __restrict__ wpk)
{
    int idx = blockIdx.x * 256 + threadIdx.x;   // 4096 total
    int t = idx >> 8;
    int lane = idx & 63;
    const float* W = (t < 8) ? Wl : Wr;
    int col = ((t & 7) << 4) + (lane & 15);
    int k0 = (((idx >> 6) & 3) << 5) + ((lane >> 4) << 3);
    __half tmp[8];
#pragma unroll
    for (int j = 0; j < 8; j++)
        tmp[j] = __float2half(W[(size_t)(k0 + j) * 128 + col]);
    *(uint4*)(wpk + ((size_t)idx << 3)) = *(uint4*)tmp;
}

// ---------------------------------------------------------------------------
// MFMA dual GEMM: xlh = fp16(in @ Wl), xr = in @ Wr (f32).
// One wave per 16 nodes; no LDS, no barriers. A-frags from global f32->cvt,
// B-frags from packed wpk (L2-hot). 16 N-tiles x 4 K-steps = 64 MFMA/wave.
// ---------------------------------------------------------------------------
__global__ __launch_bounds__(256) void k_mgemm(
    const float* __restrict__ in, const __half* __restrict__ wpk,
    __half* __restrict__ xlh, float* __restrict__ xr)
{
    const int w = threadIdx.x >> 6;
    const int lane = threadIdx.x & 63;
    const int nodebase = blockIdx.x * 64 + w * 16;
    const int lrow = lane & 15;
    const int kb = lane >> 4;                   // k-block (8 k values)

    const int nload = min(nodebase + lrow, NN - 1);
    const float* xp = in + (size_t)nload * 128 + (kb << 3);

    half8 a[4];
#pragma unroll
    for (int kf = 0; kf < 4; kf++) {
        float4 f0 = *(const float4*)(xp + kf * 32);
        float4 f1 = *(const float4*)(xp + kf * 32 + 4);
        half8 hh;
        hh[0] = (_Float16)f0.x; hh[1] = (_Float16)f0.y;
        hh[2] = (_Float16)f0.z; hh[3] = (_Float16)f0.w;
        hh[4] = (_Float16)f1.x; hh[5] = (_Float16)f1.y;
        hh[6] = (_Float16)f1.z; hh[7] = (_Float16)f1.w;
        a[kf] = hh;
    }

    const uint4* wp = (const uint4*)wpk + lane;

#pragma unroll
    for (int t = 0; t < 16; t++) {
        f32x4 acc = {0.f, 0.f, 0.f, 0.f};
#pragma unroll
        for (int kf = 0; kf < 4; kf++) {
            uint4 bu = wp[(t * 4 + kf) * 64];
            half8 b = *(half8*)&bu;
            acc = __builtin_amdgcn_mfma_f32_16x16x32_f16(a[kf], b, acc, 0, 0, 0);
        }
        int col = ((t & 7) << 4) + lrow;
#pragma unroll
        for (int i = 0; i < 4; i++) {
            int node = nodebase + kb * 4 + i;
            if (node < NN) {
                if (t < 8) xlh[(size_t)node * 128 + col] = __float2half(acc[i]);
                else       xr [(size_t)node * 128 + col] = acc[i];
            }
        }
    }
}

// ---------------------------------------------------------------------------
// CSR build: hist -> hierarchical scan (3 parallel phases, fill fused).
// ---------------------------------------------------------------------------
__global__ __launch_bounds__(256) void k_hist(
    const int* __restrict__ ei, int* __restrict__ deg)
{
    int e = blockIdx.x * 256 + threadIdx.x;
    if (e < NE) atomicAdd(deg + ei[NE + e], 1);
}

__device__ __forceinline__ int block_scan_incl(int v, int t)
{
    __shared__ int sm[256];
    sm[t] = v;
    __syncthreads();
#pragma unroll
    for (int off = 1; off < 256; off <<= 1) {
        int u = (t >= off) ? sm[t - off] : 0;
        __syncthreads();
        sm[t] += u;
        __syncthreads();
    }
    return sm[t];
}

__global__ __launch_bounds__(256) void k_scan1(
    const int* __restrict__ deg, int* __restrict__ rowptr,
    int* __restrict__ bsum)
{
    int t = threadIdx.x;
    int i = blockIdx.x * 256 + t;
    int v = (i < NN) ? deg[i] + 1 : 0;  // +1 = self-loop
    int inc = block_scan_incl(v, t);
    if (i < NN) rowptr[i] = inc - v;
    if (t == 255) bsum[blockIdx.x] = inc;
}

__global__ __launch_bounds__(256) void k_scan2(int* __restrict__ bsum)
{
    int t = threadIdx.x;
    int v = (t < NB) ? bsum[t] : 0;
    int inc = block_scan_incl(v, t);
    if (t < NB) bsum[t] = inc - v;
}

__global__ __launch_bounds__(256) void k_scan3(
    int* __restrict__ rowptr, const int* __restrict__ bsum,
    int* __restrict__ nxt, int* __restrict__ esrc)
{
    int i = blockIdx.x * 256 + threadIdx.x;
    if (i < NN) {
        int r = rowptr[i] + bsum[blockIdx.x];
        rowptr[i] = r;
        esrc[r] = i;
        nxt[i] = r + 1;
    }
    if (i == 0) rowptr[NN] = NE + NN;
}

__global__ __launch_bounds__(256) void k_scatter(
    const int* __restrict__ ei, int* __restrict__ nxt,
    int* __restrict__ esrc)
{
    int e = blockIdx.x * 256 + threadIdx.x;
    if (e >= NE) return;
    int s = ei[e], d = ei[NE + e];
    int pos = atomicAdd(nxt + d, 1);
    esrc[pos] = s;
}

// ---------------------------------------------------------------------------
// GAT core: one wave per dst node; four 16-lane groups, 4 edges per step.
// ---------------------------------------------------------------------------
__device__ __forceinline__ void gat_core(
    const char* __restrict__ xlb, const int* __restrict__ esrc,
    int beg, int end, int lane, const float* xr8, const float* at8,
    float* acc, float& den)
{
    const int g = lane >> 4;
    const unsigned qb = (unsigned)((lane & 15) << 4);
#pragma unroll
    for (int i = 0; i < 8; i++) acc[i] = 0.f;
    den = 0.f;

    for (int sc = beg; sc < end; sc += 64) {
        const int nv = min(end - sc, 64);
        const int nit = (nv + 3) >> 2;
        int myidx = esrc[sc + min(lane, nv - 1)];

        auto LD = [&](int j) -> uint4 {
            int t = (j << 2) + g;
            int s = __shfl(myidx, min(t, nv - 1), 64);
            unsigned off = ((unsigned)s << 8) | qb;
            return *(const uint4*)(xlb + off);
        };

        uint4 A = LD(0);
        uint4 B = LD(nit > 1 ? 1 : 0);
        for (int jj = 0; jj < nit; ++jj) {
            uint4 C = LD(min(jj + 2, nit - 1));

            float xl[8];
            float2 f;
            f = __half22float2(*(__half2*)&A.x); xl[0] = f.x; xl[1] = f.y;
            f = __half22float2(*(__half2*)&A.y); xl[2] = f.x; xl[3] = f.y;
            f = __half22float2(*(__half2*)&A.z); xl[4] = f.x; xl[5] = f.y;
            f = __half22float2(*(__half2*)&A.w); xl[6] = f.x; xl[7] = f.y;

            float e = 0.f;
#pragma unroll
            for (int i = 0; i < 8; i++) {
                float t2 = xl[i] + xr8[i];
                float l = fmaxf(t2, 0.2f * t2);
                e = fmaf(l, at8[i], e);
            }
#pragma unroll
            for (int off = 8; off; off >>= 1) e += __shfl_xor(e, off, 64);

            int t = (jj << 2) + g;
            float p = (t < nv) ? __expf(fminf(e, 80.f)) : 0.f;
            den += p;
#pragma unroll
            for (int i = 0; i < 8; i++) acc[i] = fmaf(p, xl[i], acc[i]);

            A = B; B = C;
        }
    }

#pragma unroll
    for (int off = 16; off < 64; off <<= 1) {
        den += __shfl_xor(den, off, 64);
#pragma unroll
        for (int i = 0; i < 8; i++) acc[i] += __shfl_xor(acc[i], off, 64);
    }
}

// layer1: fused normalize + bias + ReLU + LayerNorm -> h (f32)
__global__ __launch_bounds__(256, 6) void k_gat1(
    const char* __restrict__ xlb, const float* __restrict__ xr,
    const float* __restrict__ att, const int* __restrict__ rowptr,
    const int* __restrict__ esrc, const float* __restrict__ bias,
    const float* __restrict__ g_ln, const float* __restrict__ b_ln,
    float* __restrict__ h)
{
    int d = (int)((blockIdx.x * 256 + threadIdx.x) >> 6);
    int lane = threadIdx.x & 63;
    if (d >= NN) return;
    int q = lane & 15;

    float xr8[8], at8[8];
    {
        float4 a = *(const float4*)(xr + (size_t)d * 128 + q * 8);
        float4 b = *(const float4*)(xr + (size_t)d * 128 + q * 8 + 4);
        xr8[0]=a.x; xr8[1]=a.y; xr8[2]=a.z; xr8[3]=a.w;
        xr8[4]=b.x; xr8[5]=b.y; xr8[6]=b.z; xr8[7]=b.w;
        float4 c = *(const float4*)(att + q * 8);
        float4 e = *(const float4*)(att + q * 8 + 4);
        at8[0]=c.x; at8[1]=c.y; at8[2]=c.z; at8[3]=c.w;
        at8[4]=e.x; at8[5]=e.y; at8[6]=e.z; at8[7]=e.w;
    }

    float acc[8]; float den;
    gat_core(xlb, esrc, rowptr[d], rowptr[d + 1], lane, xr8, at8, acc, den);

    float inv = 1.f / (den + 1e-16f);
    float x[8];
    {
        float4 a = *(const float4*)(bias + q * 8);
        float4 b = *(const float4*)(bias + q * 8 + 4);
        float bb[8] = {a.x,a.y,a.z,a.w,b.x,b.y,b.z,b.w};
#pragma unroll
        for (int i = 0; i < 8; i++) x[i] = fmaxf(fmaf(acc[i], inv, bb[i]), 0.f);
    }

    float s1 = 0.f, s2 = 0.f;
#pragma unroll
    for (int i = 0; i < 8; i++) { s1 += x[i]; s2 += x[i] * x[i]; }
#pragma unroll
    for (int off = 8; off; off >>= 1) {
        s1 += __shfl_xor(s1, off, 64);
        s2 += __shfl_xor(s2, off, 64);
    }
    float mu = s1 * (1.f / 128.f);
    float var = s2 * (1.f / 128.f) - mu * mu;
    float rstd = rsqrtf(var + 1e-5f);

    if (lane < 16) {
        float4 ga = *(const float4*)(g_ln + q * 8);
        float4 gb = *(const float4*)(g_ln + q * 8 + 4);
        float4 ba = *(const float4*)(b_ln + q * 8);
        float4 bb = *(const float4*)(b_ln + q * 8 + 4);
        float4 o0, o1;
        o0.x = (x[0]-mu)*rstd*ga.x + ba.x;
        o0.y = (x[1]-mu)*rstd*ga.y + ba.y;
        o0.z = (x[2]-mu)*rstd*ga.z + ba.z;
        o0.w = (x[3]-mu)*rstd*ga.w + ba.w;
        o1.x = (x[4]-mu)*rstd*gb.x + bb.x;
        o1.y = (x[5]-mu)*rstd*gb.y + bb.y;
        o1.z = (x[6]-mu)*rstd*gb.z + bb.z;
        o1.w = (x[7]-mu)*rstd*gb.w + bb.w;
        *(float4*)(h + (size_t)d * 128 + q * 8)     = o0;
        *(float4*)(h + (size_t)d * 128 + q * 8 + 4) = o1;
    }
}

// layer2: fused normalize + bias -> h2 (plain write)
__global__ __launch_bounds__(256, 6) void k_gat2(
    const char* __restrict__ xlb, const float* __restrict__ xr,
    const float* __restrict__ att, const int* __restrict__ rowptr,
    const int* __restrict__ esrc, const float* __restrict__ bias,
    float* __restrict__ h2)
{
    int d = (int)((blockIdx.x * 256 + threadIdx.x) >> 6);
    int lane = threadIdx.x & 63;
    if (d >= NN) return;
    int q = lane & 15;

    float xr8[8], at8[8];
    {
        float4 a = *(const float4*)(xr + (size_t)d * 128 + q * 8);
        float4 b = *(const float4*)(xr + (size_t)d * 128 + q * 8 + 4);
        xr8[0]=a.x; xr8[1]=a.y; xr8[2]=a.z; xr8[3]=a.w;
        xr8[4]=b.x; xr8[5]=b.y; xr8[6]=b.z; xr8[7]=b.w;
        float4 c = *(const float4*)(att + q * 8);
        float4 e = *(const float4*)(att + q * 8 + 4);
        at8[0]=c.x; at8[1]=c.y; at8[2]=c.z; at8[3]=c.w;
        at8[4]=e.x; at8[5]=e.y; at8[6]=e.z; at8[7]=e.w;
    }

    float acc[8]; float den;
    gat_core(xlb, esrc, rowptr[d], rowptr[d + 1], lane, xr8, at8, acc, den);

    float inv = 1.f / (den + 1e-16f);
    if (lane < 16) {
        float4 a = *(const float4*)(bias + q * 8);
        float4 b = *(const float4*)(bias + q * 8 + 4);
        float4 o0, o1;
        o0.x = fmaf(acc[0], inv, a.x);
        o0.y = fmaf(acc[1], inv, a.y);
        o0.z = fmaf(acc[2], inv, a.z);
        o0.w = fmaf(acc[3], inv, a.w);
        o1.x = fmaf(acc[4], inv, b.x);
        o1.y = fmaf(acc[5], inv, b.y);
        o1.z = fmaf(acc[6], inv, b.z);
        o1.w = fmaf(acc[7], inv, b.w);
        *(float4*)(h2 + (size_t)d * 128 + q * 8)     = o0;
        *(float4*)(h2 + (size_t)d * 128 + q * 8 + 4) = o1;
    }
}

// ---------------------------------------------------------------------------
#define NPB 100
__global__ __launch_bounds__(128) void k_pool(
    const float* __restrict__ h2, const int* __restrict__ batch,
    float* __restrict__ pooled, float* __restrict__ cnt)
{
    int n0 = blockIdx.x * NPB;
    int n1 = min(n0 + NPB, NN);
    if (n0 >= NN) return;
    int f = threadIdx.x;

    float s = 0.f;
    int c = 0;
    int curg = batch[n0];
    for (int n = n0; n < n1; n++) {
        int g = batch[n];
        if (g != curg) {
            atomicAdd(pooled + (size_t)curg * 128 + f, s);
            if (f == 0) atomicAdd(cnt + curg, (float)c);
            s = 0.f; c = 0; curg = g;
        }
        s += h2[(size_t)n * 128 + f];
        c++;
    }
    atomicAdd(pooled + (size_t)curg * 128 + f, s);
    if (f == 0) atomicAdd(cnt + curg, (float)c);
}

// ---------------------------------------------------------------------------
__global__ __launch_bounds__(256) void k_linear(
    const float* __restrict__ pooled, const float* __restrict__ cnt,
    const float* __restrict__ W, const float* __restrict__ b,
    float* __restrict__ out)
{
    int idx = blockIdx.x * 256 + threadIdx.x;
    if (idx >= NG * NC) return;
    int g = idx / NC, c = idx % NC;
    float invc = 1.f / fmaxf(cnt[g], 1.f);
    float s = 0.f;
    for (int k = 0; k < HID; k++)
        s = fmaf(pooled[(size_t)g * 128 + k], W[(size_t)k * NC + c], s);
    out[idx] = fmaf(s, invc, b[c]);
}

// ---------------------------------------------------------------------------
extern "C" void kernel_launch(void* const* d_in, const int* in_sizes, int n_in,
                              void* d_out, int out_size, void* d_ws, size_t ws_size,
                              hipStream_t stream)
{
    const float* x     = (const float*)d_in[0];
    const int*   ei    = (const int*)d_in[1];
    const int*   batch = (const int*)d_in[2];
    const float* Wl1   = (const float*)d_in[3];
    const float* Wr1   = (const float*)d_in[4];
    const float* att1  = (const float*)d_in[5];
    const float* b1    = (const float*)d_in[6];
    const float* g_ln  = (const float*)d_in[7];
    const float* b_ln  = (const float*)d_in[8];
    const float* Wl2   = (const float*)d_in[9];
    const float* Wr2   = (const float*)d_in[10];
    const float* att2  = (const float*)d_in[11];
    const float* b2    = (const float*)d_in[12];
    const float* Wlin  = (const float*)d_in[13];
    const float* blin  = (const float*)d_in[14];
    float* out = (float*)d_out;

    char* ws = (char*)d_ws;
    __half* xlh16 = (__half*)ws;                          // 12.8 MB
    char* xlb    = ws;                                    // byte view
    float* xr    = (float*)(ws + (size_t)NN * 256);       // 25.6 MB
    float* h     = xr + (size_t)NN * HID;                 // 25.6 MB
    float* h2    = h + (size_t)NN * HID;                  // 25.6 MB
    float* pooled = h2 + (size_t)NN * HID;                // 128 KB
    float* cnt   = pooled + (size_t)NG * HID;             // 1 KB
    int* deg    = (int*)(cnt + NG);                       // NN
    int* rowptr = deg + NN;                               // NN+1
    int* nxt    = rowptr + NN + 1;                        // NN
    int* bsum   = nxt + NN;                               // 256
    int* esrc   = bsum + 256;                             // NE+NN
    __half* wpk1 = (__half*)(esrc + NE + NN);             // 64 KB
    __half* wpk2 = wpk1 + 32768;                          // 64 KB

    const int edge_blocks = (NE + 255) / 256;
    const int mg_blocks   = (NN + 63) / 64;               // 64 nodes/block
    const int gat_blocks  = (NN * 64 + 255) / 256;        // wave per node

    // ---- W pack (independent; issue first) ----
    k_wpack<<<16, 256, 0, stream>>>(Wl1, Wr1, wpk1);
    k_wpack<<<16, 256, 0, stream>>>(Wl2, Wr2, wpk2);

    // ---- CSR build ----
    hipMemsetAsync(deg, 0, NN * sizeof(int), stream);
    k_hist<<<edge_blocks, 256, 0, stream>>>(ei, deg);
    k_scan1<<<NB, 256, 0, stream>>>(deg, rowptr, bsum);
    k_scan2<<<1, 256, 0, stream>>>(bsum);
    k_scan3<<<NB, 256, 0, stream>>>(rowptr, bsum, nxt, esrc);
    k_scatter<<<edge_blocks, 256, 0, stream>>>(ei, nxt, esrc);

    hipMemsetAsync(pooled, 0, ((size_t)NG * HID + NG) * sizeof(float), stream);

    // ---- layer 1 ----
    k_mgemm<<<mg_blocks, 256, 0, stream>>>(x, wpk1, xlh16, xr);
    k_gat1<<<gat_blocks, 256, 0, stream>>>(xlb, xr, att1, rowptr, esrc,
                                           b1, g_ln, b_ln, h);

    // ---- layer 2 ----
    k_mgemm<<<mg_blocks, 256, 0, stream>>>(h, wpk2, xlh16, xr);
    k_gat2<<<gat_blocks, 256, 0, stream>>>(xlb, xr, att2, rowptr, esrc,
                                           b2, h2);

    // ---- pool + head ----
    k_pool<<<(NN + NPB - 1) / NPB, 128, 0, stream>>>(h2, batch, pooled, cnt);
    k_linear<<<(NG * NC + 255) / 256, 256, 0, stream>>>(pooled, cnt, Wlin, blin, out);
}

// Round 10
// 227.441 us; speedup vs baseline: 2.6973x; 1.1995x over previous
//
#include <hip/hip_runtime.h>
#include <hip/hip_bf16.h>
#include <hip/hip_fp16.h>

#define NN 50000
#define NE 800000
#define HID 128
#define NG 256
#define NC 10
#define NB 196    // buckets of 256 dst nodes
#define CHUNK 4096

using half8 = __attribute__((ext_vector_type(8))) _Float16;
using f32x4 = __attribute__((ext_vector_type(4))) float;

// ---------------------------------------------------------------------------
// W pack: [Wl|Wr] f32 [128][128] -> fragment-ready fp16 (see R8 layout).
// ---------------------------------------------------------------------------
__global__ __launch_bounds__(256) void k_wpack(
    const float* __restrict__ Wl, const float* __restrict__ Wr,
    __half* __restrict__ wpk)
{
    int idx = blockIdx.x * 256 + threadIdx.x;   // 4096 total
    int t = idx >> 8;
    int lane = idx & 63;
    const float* W = (t < 8) ? Wl : Wr;
    int col = ((t & 7) << 4) + (lane & 15);
    int k0 = (((idx >> 6) & 3) << 5) + ((lane >> 4) << 3);
    __half tmp[8];
#pragma unroll
    for (int j = 0; j < 8; j++)
        tmp[j] = __float2half(W[(size_t)(k0 + j) * 128 + col]);
    *(uint4*)(wpk + ((size_t)idx << 3)) = *(uint4*)tmp;
}

// ---------------------------------------------------------------------------
// MFMA dual GEMM: xlh = fp16(in @ Wl), xr = in @ Wr (f32).
// ---------------------------------------------------------------------------
__global__ __launch_bounds__(256) void k_mgemm(
    const float* __restrict__ in, const __half* __restrict__ wpk,
    __half* __restrict__ xlh, float* __restrict__ xr)
{
    const int w = threadIdx.x >> 6;
    const int lane = threadIdx.x & 63;
    const int nodebase = blockIdx.x * 64 + w * 16;
    const int lrow = lane & 15;
    const int kb = lane >> 4;

    const int nload = min(nodebase + lrow, NN - 1);
    const float* xp = in + (size_t)nload * 128 + (kb << 3);

    half8 a[4];
#pragma unroll
    for (int kf = 0; kf < 4; kf++) {
        float4 f0 = *(const float4*)(xp + kf * 32);
        float4 f1 = *(const float4*)(xp + kf * 32 + 4);
        half8 hh;
        hh[0] = (_Float16)f0.x; hh[1] = (_Float16)f0.y;
        hh[2] = (_Float16)f0.z; hh[3] = (_Float16)f0.w;
        hh[4] = (_Float16)f1.x; hh[5] = (_Float16)f1.y;
        hh[6] = (_Float16)f1.z; hh[7] = (_Float16)f1.w;
        a[kf] = hh;
    }

    const uint4* wp = (const uint4*)wpk + lane;

#pragma unroll
    for (int t = 0; t < 16; t++) {
        f32x4 acc = {0.f, 0.f, 0.f, 0.f};
#pragma unroll
        for (int kf = 0; kf < 4; kf++) {
            uint4 bu = wp[(t * 4 + kf) * 64];
            half8 b = *(half8*)&bu;
            acc = __builtin_amdgcn_mfma_f32_16x16x32_f16(a[kf], b, acc, 0, 0, 0);
        }
        int col = ((t & 7) << 4) + lrow;
#pragma unroll
        for (int i = 0; i < 4; i++) {
            int node = nodebase + kb * 4 + i;
            if (node < NN) {
                if (t < 8) xlh[(size_t)node * 128 + col] = __float2half(acc[i]);
                else       xr [(size_t)node * 128 + col] = acc[i];
            }
        }
    }
}

// ---------------------------------------------------------------------------
// Bucketed CSR build. Bucket b = dst >> 8 covers nodes [b*256, b*256+256).
// pairbuf element: (src << 8) | (dst & 255)   (src < 2^16, fits)
// ---------------------------------------------------------------------------
__device__ __forceinline__ int block_scan_incl(int v, int t)
{
    __shared__ int sm[256];
    sm[t] = v;
    __syncthreads();
#pragma unroll
    for (int off = 1; off < 256; off <<= 1) {
        int u = (t >= off) ? sm[t - off] : 0;
        __syncthreads();
        sm[t] += u;
        __syncthreads();
    }
    return sm[t];
}

// 1) bucket histogram
__global__ __launch_bounds__(256) void k_bcount(
    const int* __restrict__ ei, int* __restrict__ bcnt)
{
    __shared__ int lc[256];
    int t = threadIdx.x;
    lc[t] = 0;
    __syncthreads();
    for (int e = blockIdx.x * 256 + t; e < NE; e += gridDim.x * 256)
        atomicAdd(&lc[ei[NE + e] >> 8], 1);
    __syncthreads();
    if (lc[t]) atomicAdd(&bcnt[t], lc[t]);
}

// 2) bucket scans: pair-buffer bases + esrc row-region bases
__global__ __launch_bounds__(256) void k_bscan(
    const int* __restrict__ bcnt, int* __restrict__ ebase,
    int* __restrict__ cursor, int* __restrict__ rowreg)
{
    int t = threadIdx.x;
    int bc = (t < NB) ? bcnt[t] : 0;
    int nodes = (t < NB) ? min(256, NN - t * 256) : 0;
    int inc1 = block_scan_incl(bc, t);
    int eb = inc1 - bc;
    int inc2 = block_scan_incl(bc + nodes, t);
    int rr = inc2 - (bc + nodes);
    if (t < NB) { ebase[t] = eb; cursor[t] = eb; rowreg[t] = rr; }
}

// 3) chunk-local LDS counting sort by bucket -> grouped global writes
__global__ __launch_bounds__(256) void k_bscatter(
    const int* __restrict__ ei, int* __restrict__ cursor,
    unsigned* __restrict__ pairbuf)
{
    __shared__ int lcnt[256], cstart[256], lcur[256], gpos[256];
    __shared__ unsigned sorted[CHUNK];
    __shared__ unsigned char sortedB[CHUNK];
    const int t = threadIdx.x;
    const int base = blockIdx.x * CHUNK;
    const int n = min(CHUNK, NE - base);
    if (n <= 0) return;

    lcnt[t] = 0;
    __syncthreads();

    unsigned pk[16];
    int bk[16];
#pragma unroll
    for (int i = 0; i < 16; i++) {
        int off = i * 256 + t;
        bk[i] = -1;
        if (off < n) {
            int e = base + off;
            int s = ei[e], d = ei[NE + e];
            bk[i] = d >> 8;
            pk[i] = ((unsigned)s << 8) | (unsigned)(d & 255);
            atomicAdd(&lcnt[bk[i]], 1);
        }
    }
    __syncthreads();

    int v = lcnt[t];
    int inc = block_scan_incl(v, t);
    cstart[t] = inc - v;
    lcur[t] = inc - v;
    __syncthreads();
    gpos[t] = (v > 0) ? atomicAdd(&cursor[t], v) : 0;
    __syncthreads();

#pragma unroll
    for (int i = 0; i < 16; i++) {
        if (bk[i] >= 0) {
            int r = atomicAdd(&lcur[bk[i]], 1);
            sorted[r] = pk[i];
            sortedB[r] = (unsigned char)bk[i];
        }
    }
    __syncthreads();

    for (int j = t; j < n; j += 256) {
        int b = sortedB[j];
        pairbuf[gpos[b] + (j - cstart[b])] = sorted[j];
    }
}

// 4) per-bucket: exact rowptr + self-loop + esrc placement (L2-local region)
__global__ __launch_bounds__(256) void k_bbuild(
    const unsigned* __restrict__ pairbuf, const int* __restrict__ bcnt,
    const int* __restrict__ ebase, const int* __restrict__ rowreg,
    int* __restrict__ rowptr, int* __restrict__ esrc)
{
    __shared__ int ncnt[256], cur[256];
    const int b = blockIdx.x;
    const int t = threadIdx.x;
    const int node0 = b * 256;
    const int nnodes = min(256, NN - node0);
    const int cnt = bcnt[b];
    const int be = ebase[b];
    const int row0 = rowreg[b];

    ncnt[t] = 0;
    __syncthreads();
    for (int i = t; i < cnt; i += 256)
        atomicAdd(&ncnt[pairbuf[be + i] & 255u], 1);
    __syncthreads();

    int v = (t < nnodes) ? ncnt[t] + 1 : 0;  // +1 self-loop
    int inc = block_scan_incl(v, t);
    int rb = row0 + inc - v;
    if (t < nnodes) {
        rowptr[node0 + t] = rb;
        esrc[rb] = node0 + t;   // self-loop in slot 0 of the row
        cur[t] = rb + 1;
    }
    if (b == NB - 1 && t == 0) rowptr[NN] = NE + NN;
    __syncthreads();

    for (int i = t; i < cnt; i += 256) {
        unsigned p = pairbuf[be + i];
        int pos = atomicAdd(&cur[p & 255u], 1);
        esrc[pos] = (int)(p >> 8);
    }
}

// ---------------------------------------------------------------------------
// GAT core: one wave per dst node; four 16-lane groups, 4 edges per step.
// ---------------------------------------------------------------------------
__device__ __forceinline__ void gat_core(
    const char* __restrict__ xlb, const int* __restrict__ esrc,
    int beg, int end, int lane, const float* xr8, const float* at8,
    float* acc, float& den)
{
    const int g = lane >> 4;
    const unsigned qb = (unsigned)((lane & 15) << 4);
#pragma unroll
    for (int i = 0; i < 8; i++) acc[i] = 0.f;
    den = 0.f;

    for (int sc = beg; sc < end; sc += 64) {
        const int nv = min(end - sc, 64);
        const int nit = (nv + 3) >> 2;
        int myidx = esrc[sc + min(lane, nv - 1)];

        auto LD = [&](int j) -> uint4 {
            int t = (j << 2) + g;
            int s = __shfl(myidx, min(t, nv - 1), 64);
            unsigned off = ((unsigned)s << 8) | qb;
            return *(const uint4*)(xlb + off);
        };

        uint4 A = LD(0);
        uint4 B = LD(nit > 1 ? 1 : 0);
        for (int jj = 0; jj < nit; ++jj) {
            uint4 C = LD(min(jj + 2, nit - 1));

            float xl[8];
            float2 f;
            f = __half22float2(*(__half2*)&A.x); xl[0] = f.x; xl[1] = f.y;
            f = __half22float2(*(__half2*)&A.y); xl[2] = f.x; xl[3] = f.y;
            f = __half22float2(*(__half2*)&A.z); xl[4] = f.x; xl[5] = f.y;
            f = __half22float2(*(__half2*)&A.w); xl[6] = f.x; xl[7] = f.y;

            float e = 0.f;
#pragma unroll
            for (int i = 0; i < 8; i++) {
                float t2 = xl[i] + xr8[i];
                float l = fmaxf(t2, 0.2f * t2);
                e = fmaf(l, at8[i], e);
            }
#pragma unroll
            for (int off = 8; off; off >>= 1) e += __shfl_xor(e, off, 64);

            int t = (jj << 2) + g;
            float p = (t < nv) ? __expf(fminf(e, 80.f)) : 0.f;
            den += p;
#pragma unroll
            for (int i = 0; i < 8; i++) acc[i] = fmaf(p, xl[i], acc[i]);

            A = B; B = C;
        }
    }

#pragma unroll
    for (int off = 16; off < 64; off <<= 1) {
        den += __shfl_xor(den, off, 64);
#pragma unroll
        for (int i = 0; i < 8; i++) acc[i] += __shfl_xor(acc[i], off, 64);
    }
}

// layer1: fused normalize + bias + ReLU + LayerNorm -> h (f32)
__global__ __launch_bounds__(256, 6) void k_gat1(
    const char* __restrict__ xlb, const float* __restrict__ xr,
    const float* __restrict__ att, const int* __restrict__ rowptr,
    const int* __restrict__ esrc, const float* __restrict__ bias,
    const float* __restrict__ g_ln, const float* __restrict__ b_ln,
    float* __restrict__ h)
{
    int d = (int)((blockIdx.x * 256 + threadIdx.x) >> 6);
    int lane = threadIdx.x & 63;
    if (d >= NN) return;
    int q = lane & 15;

    float xr8[8], at8[8];
    {
        float4 a = *(const float4*)(xr + (size_t)d * 128 + q * 8);
        float4 b = *(const float4*)(xr + (size_t)d * 128 + q * 8 + 4);
        xr8[0]=a.x; xr8[1]=a.y; xr8[2]=a.z; xr8[3]=a.w;
        xr8[4]=b.x; xr8[5]=b.y; xr8[6]=b.z; xr8[7]=b.w;
        float4 c = *(const float4*)(att + q * 8);
        float4 e = *(const float4*)(att + q * 8 + 4);
        at8[0]=c.x; at8[1]=c.y; at8[2]=c.z; at8[3]=c.w;
        at8[4]=e.x; at8[5]=e.y; at8[6]=e.z; at8[7]=e.w;
    }

    float acc[8]; float den;
    gat_core(xlb, esrc, rowptr[d], rowptr[d + 1], lane, xr8, at8, acc, den);

    float inv = 1.f / (den + 1e-16f);
    float x[8];
    {
        float4 a = *(const float4*)(bias + q * 8);
        float4 b = *(const float4*)(bias + q * 8 + 4);
        float bb[8] = {a.x,a.y,a.z,a.w,b.x,b.y,b.z,b.w};
#pragma unroll
        for (int i = 0; i < 8; i++) x[i] = fmaxf(fmaf(acc[i], inv, bb[i]), 0.f);
    }

    float s1 = 0.f, s2 = 0.f;
#pragma unroll
    for (int i = 0; i < 8; i++) { s1 += x[i]; s2 += x[i] * x[i]; }
#pragma unroll
    for (int off = 8; off; off >>= 1) {
        s1 += __shfl_xor(s1, off, 64);
        s2 += __shfl_xor(s2, off, 64);
    }
    float mu = s1 * (1.f / 128.f);
    float var = s2 * (1.f / 128.f) - mu * mu;
    float rstd = rsqrtf(var + 1e-5f);

    if (lane < 16) {
        float4 ga = *(const float4*)(g_ln + q * 8);
        float4 gb = *(const float4*)(g_ln + q * 8 + 4);
        float4 ba = *(const float4*)(b_ln + q * 8);
        float4 bb = *(const float4*)(b_ln + q * 8 + 4);
        float4 o0, o1;
        o0.x = (x[0]-mu)*rstd*ga.x + ba.x;
        o0.y = (x[1]-mu)*rstd*ga.y + ba.y;
        o0.z = (x[2]-mu)*rstd*ga.z + ba.z;
        o0.w = (x[3]-mu)*rstd*ga.w + ba.w;
        o1.x = (x[4]-mu)*rstd*gb.x + bb.x;
        o1.y = (x[5]-mu)*rstd*gb.y + bb.y;
        o1.z = (x[6]-mu)*rstd*gb.z + bb.z;
        o1.w = (x[7]-mu)*rstd*gb.w + bb.w;
        *(float4*)(h + (size_t)d * 128 + q * 8)     = o0;
        *(float4*)(h + (size_t)d * 128 + q * 8 + 4) = o1;
    }
}

// layer2: fused normalize + bias -> h2 (plain write)
__global__ __launch_bounds__(256, 6) void k_gat2(
    const char* __restrict__ xlb, const float* __restrict__ xr,
    const float* __restrict__ att, const int* __restrict__ rowptr,
    const int* __restrict__ esrc, const float* __restrict__ bias,
    float* __restrict__ h2)
{
    int d = (int)((blockIdx.x * 256 + threadIdx.x) >> 6);
    int lane = threadIdx.x & 63;
    if (d >= NN) return;
    int q = lane & 15;

    float xr8[8], at8[8];
    {
        float4 a = *(const float4*)(xr + (size_t)d * 128 + q * 8);
        float4 b = *(const float4*)(xr + (size_t)d * 128 + q * 8 + 4);
        xr8[0]=a.x; xr8[1]=a.y; xr8[2]=a.z; xr8[3]=a.w;
        xr8[4]=b.x; xr8[5]=b.y; xr8[6]=b.z; xr8[7]=b.w;
        float4 c = *(const float4*)(att + q * 8);
        float4 e = *(const float4*)(att + q * 8 + 4);
        at8[0]=c.x; at8[1]=c.y; at8[2]=c.z; at8[3]=c.w;
        at8[4]=e.x; at8[5]=e.y; at8[6]=e.z; at8[7]=e.w;
    }

    float acc[8]; float den;
    gat_core(xlb, esrc, rowptr[d], rowptr[d + 1], lane, xr8, at8, acc, den);

    float inv = 1.f / (den + 1e-16f);
    if (lane < 16) {
        float4 a = *(const float4*)(bias + q * 8);
        float4 b = *(const float4*)(bias + q * 8 + 4);
        float4 o0, o1;
        o0.x = fmaf(acc[0], inv, a.x);
        o0.y = fmaf(acc[1], inv, a.y);
        o0.z = fmaf(acc[2], inv, a.z);
        o0.w = fmaf(acc[3], inv, a.w);
        o1.x = fmaf(acc[4], inv, b.x);
        o1.y = fmaf(acc[5], inv, b.y);
        o1.z = fmaf(acc[6], inv, b.z);
        o1.w = fmaf(acc[7], inv, b.w);
        *(float4*)(h2 + (size_t)d * 128 + q * 8)     = o0;
        *(float4*)(h2 + (size_t)d * 128 + q * 8 + 4) = o1;
    }
}

// ---------------------------------------------------------------------------
#define NPB 100
__global__ __launch_bounds__(128) void k_pool(
    const float* __restrict__ h2, const int* __restrict__ batch,
    float* __restrict__ pooled, float* __restrict__ cnt)
{
    int n0 = blockIdx.x * NPB;
    int n1 = min(n0 + NPB, NN);
    if (n0 >= NN) return;
    int f = threadIdx.x;

    float s = 0.f;
    int c = 0;
    int curg = batch[n0];
    for (int n = n0; n < n1; n++) {
        int g = batch[n];
        if (g != curg) {
            atomicAdd(pooled + (size_t)curg * 128 + f, s);
            if (f == 0) atomicAdd(cnt + curg, (float)c);
            s = 0.f; c = 0; curg = g;
        }
        s += h2[(size_t)n * 128 + f];
        c++;
    }
    atomicAdd(pooled + (size_t)curg * 128 + f, s);
    if (f == 0) atomicAdd(cnt + curg, (float)c);
}

// ---------------------------------------------------------------------------
__global__ __launch_bounds__(256) void k_linear(
    const float* __restrict__ pooled, const float* __restrict__ cnt,
    const float* __restrict__ W, const float* __restrict__ b,
    float* __restrict__ out)
{
    int idx = blockIdx.x * 256 + threadIdx.x;
    if (idx >= NG * NC) return;
    int g = idx / NC, c = idx % NC;
    float invc = 1.f / fmaxf(cnt[g], 1.f);
    float s = 0.f;
    for (int k = 0; k < HID; k++)
        s = fmaf(pooled[(size_t)g * 128 + k], W[(size_t)k * NC + c], s);
    out[idx] = fmaf(s, invc, b[c]);
}

// ---------------------------------------------------------------------------
extern "C" void kernel_launch(void* const* d_in, const int* in_sizes, int n_in,
                              void* d_out, int out_size, void* d_ws, size_t ws_size,
                              hipStream_t stream)
{
    const float* x     = (const float*)d_in[0];
    const int*   ei    = (const int*)d_in[1];
    const int*   batch = (const int*)d_in[2];
    const float* Wl1   = (const float*)d_in[3];
    const float* Wr1   = (const float*)d_in[4];
    const float* att1  = (const float*)d_in[5];
    const float* b1    = (const float*)d_in[6];
    const float* g_ln  = (const float*)d_in[7];
    const float* b_ln  = (const float*)d_in[8];
    const float* Wl2   = (const float*)d_in[9];
    const float* Wr2   = (const float*)d_in[10];
    const float* att2  = (const float*)d_in[11];
    const float* b2    = (const float*)d_in[12];
    const float* Wlin  = (const float*)d_in[13];
    const float* blin  = (const float*)d_in[14];
    float* out = (float*)d_out;

    char* ws = (char*)d_ws;
    __half* xlh16 = (__half*)ws;                          // 12.8 MB
    char* xlb    = ws;                                    // byte view
    float* xr    = (float*)(ws + (size_t)NN * 256);       // 25.6 MB
    float* h     = xr + (size_t)NN * HID;                 // 25.6 MB
    float* h2    = h + (size_t)NN * HID;                  // 25.6 MB
    float* pooled = h2 + (size_t)NN * HID;                // 128 KB
    float* cnt   = pooled + (size_t)NG * HID;             // 1 KB
    int* rowptr  = (int*)(cnt + NG);                      // NN+1
    int* esrc    = rowptr + NN + 1;                       // NE+NN
    unsigned* pairbuf = (unsigned*)(esrc + NE + NN);      // NE (3.2 MB)
    int* bcnt    = (int*)(pairbuf + NE);                  // 256
    int* ebase   = bcnt + 256;                            // 256
    int* rowreg  = ebase + 256;                           // 256
    int* cursor  = rowreg + 256;                          // 256
    __half* wpk1 = (__half*)(cursor + 256);               // 64 KB
    __half* wpk2 = wpk1 + 32768;                          // 64 KB

    const int mg_blocks  = (NN + 63) / 64;
    const int gat_blocks = (NN * 64 + 255) / 256;
    const int sc_blocks  = (NE + CHUNK - 1) / CHUNK;      // 196

    // ---- W pack ----
    k_wpack<<<16, 256, 0, stream>>>(Wl1, Wr1, wpk1);
    k_wpack<<<16, 256, 0, stream>>>(Wl2, Wr2, wpk2);

    // ---- bucketed CSR build ----
    hipMemsetAsync(bcnt, 0, 256 * sizeof(int), stream);
    k_bcount<<<256, 256, 0, stream>>>(ei, bcnt);
    k_bscan<<<1, 256, 0, stream>>>(bcnt, ebase, cursor, rowreg);
    k_bscatter<<<sc_blocks, 256, 0, stream>>>(ei, cursor, pairbuf);
    k_bbuild<<<NB, 256, 0, stream>>>(pairbuf, bcnt, ebase, rowreg, rowptr, esrc);

    hipMemsetAsync(pooled, 0, ((size_t)NG * HID + NG) * sizeof(float), stream);

    // ---- layer 1 ----
    k_mgemm<<<mg_blocks, 256, 0, stream>>>(x, wpk1, xlh16, xr);
    k_gat1<<<gat_blocks, 256, 0, stream>>>(xlb, xr, att1, rowptr, esrc,
                                           b1, g_ln, b_ln, h);

    // ---- layer 2 ----
    k_mgemm<<<mg_blocks, 256, 0, stream>>>(h, wpk2, xlh16, xr);
    k_gat2<<<gat_blocks, 256, 0, stream>>>(xlb, xr, att2, rowptr, esrc,
                                           b2, h2);

    // ---- pool + head ----
    k_pool<<<(NN + NPB - 1) / NPB, 128, 0, stream>>>(h2, batch, pooled, cnt);
    k_linear<<<(NG * NC + 255) / 256, 256, 0, stream>>>(pooled, cnt, Wlin, blin, out);
}

// Round 11
// 219.464 us; speedup vs baseline: 2.7953x; 1.0364x over previous
//
#include <hip/hip_runtime.h>
#include <hip/hip_bf16.h>
#include <hip/hip_fp16.h>

#define NN 50000
#define NE 800000
#define HID 128
#define NG 256
#define NC 10
#define NB 196    // buckets of 256 dst nodes
#define CHUNK 4096

using half8  = __attribute__((ext_vector_type(8))) _Float16;
using half2v = __attribute__((ext_vector_type(2))) _Float16;
using f32x4  = __attribute__((ext_vector_type(4))) float;
using f32x2  = __attribute__((ext_vector_type(2))) float;

__device__ __forceinline__ float fdot2f(unsigned a, unsigned b, float c)
{
#if __has_builtin(__builtin_amdgcn_fdot2)
    return __builtin_amdgcn_fdot2(*(half2v*)&a, *(half2v*)&b, c, false);
#else
    float2 fa = __half22float2(*(__half2*)&a);
    float2 fb = __half22float2(*(__half2*)&b);
    return fmaf(fa.x, fb.x, fmaf(fa.y, fb.y, c));
#endif
}

// packed leaky_relu(xl + xr) in fp16: max(s, 0.2*s)
__device__ __forceinline__ unsigned addleaky_h2(unsigned xl, unsigned xr)
{
    half2v s = *(half2v*)&xl + *(half2v*)&xr;
    half2v l = __builtin_elementwise_max(s, s * (_Float16)0.2f);
    return *(unsigned*)&l;
}

__device__ __forceinline__ f32x2 cvt_h2(unsigned u)
{
    return __builtin_convertvector(*(half2v*)&u, f32x2);
}

// ---------------------------------------------------------------------------
// W pack: [Wl|Wr] f32 [128][128] -> fragment-ready fp16 (R8 layout).
// ---------------------------------------------------------------------------
__global__ __launch_bounds__(256) void k_wpack(
    const float* __restrict__ Wl, const float* __restrict__ Wr,
    __half* __restrict__ wpk)
{
    int idx = blockIdx.x * 256 + threadIdx.x;   // 4096 total
    int t = idx >> 8;
    int lane = idx & 63;
    const float* W = (t < 8) ? Wl : Wr;
    int col = ((t & 7) << 4) + (lane & 15);
    int k0 = (((idx >> 6) & 3) << 5) + ((lane >> 4) << 3);
    __half tmp[8];
#pragma unroll
    for (int j = 0; j < 8; j++)
        tmp[j] = __float2half(W[(size_t)(k0 + j) * 128 + col]);
    *(uint4*)(wpk + ((size_t)idx << 3)) = *(uint4*)tmp;
}

// ---------------------------------------------------------------------------
// MFMA dual GEMM: xlh = fp16(in @ Wl), xrh = fp16(in @ Wr).
// F32IN: input rows are f32 (512 B); else fp16 (256 B).
// ---------------------------------------------------------------------------
template <bool F32IN>
__global__ __launch_bounds__(256) void k_mgemm(
    const void* __restrict__ in, const __half* __restrict__ wpk,
    __half* __restrict__ xlh, __half* __restrict__ xrh)
{
    const int w = threadIdx.x >> 6;
    const int lane = threadIdx.x & 63;
    const int nodebase = blockIdx.x * 64 + w * 16;
    const int lrow = lane & 15;
    const int kb = lane >> 4;

    const int nload = min(nodebase + lrow, NN - 1);

    half8 a[4];
    if constexpr (F32IN) {
        const float* xp = (const float*)in + (size_t)nload * 128 + (kb << 3);
#pragma unroll
        for (int kf = 0; kf < 4; kf++) {
            float4 f0 = *(const float4*)(xp + kf * 32);
            float4 f1 = *(const float4*)(xp + kf * 32 + 4);
            half8 hh;
            hh[0] = (_Float16)f0.x; hh[1] = (_Float16)f0.y;
            hh[2] = (_Float16)f0.z; hh[3] = (_Float16)f0.w;
            hh[4] = (_Float16)f1.x; hh[5] = (_Float16)f1.y;
            hh[6] = (_Float16)f1.z; hh[7] = (_Float16)f1.w;
            a[kf] = hh;
        }
    } else {
        const char* xp = (const char*)in + (size_t)nload * 256 + (kb << 4);
#pragma unroll
        for (int kf = 0; kf < 4; kf++) {
            uint4 u = *(const uint4*)(xp + kf * 64);
            a[kf] = *(half8*)&u;
        }
    }

    const uint4* wp = (const uint4*)wpk + lane;

#pragma unroll
    for (int t = 0; t < 16; t++) {
        f32x4 acc = {0.f, 0.f, 0.f, 0.f};
#pragma unroll
        for (int kf = 0; kf < 4; kf++) {
            uint4 bu = wp[(t * 4 + kf) * 64];
            half8 b = *(half8*)&bu;
            acc = __builtin_amdgcn_mfma_f32_16x16x32_f16(a[kf], b, acc, 0, 0, 0);
        }
        int col = ((t & 7) << 4) + lrow;
#pragma unroll
        for (int i = 0; i < 4; i++) {
            int node = nodebase + kb * 4 + i;
            if (node < NN) {
                if (t < 8) xlh[(size_t)node * 128 + col] = __float2half(acc[i]);
                else       xrh[(size_t)node * 128 + col] = __float2half(acc[i]);
            }
        }
    }
}

// ---------------------------------------------------------------------------
// Bucketed CSR build (unchanged from R9).
// ---------------------------------------------------------------------------
__device__ __forceinline__ int block_scan_incl(int v, int t)
{
    __shared__ int sm[256];
    sm[t] = v;
    __syncthreads();
#pragma unroll
    for (int off = 1; off < 256; off <<= 1) {
        int u = (t >= off) ? sm[t - off] : 0;
        __syncthreads();
        sm[t] += u;
        __syncthreads();
    }
    return sm[t];
}

__global__ __launch_bounds__(256) void k_bcount(
    const int* __restrict__ ei, int* __restrict__ bcnt)
{
    __shared__ int lc[256];
    int t = threadIdx.x;
    lc[t] = 0;
    __syncthreads();
    for (int e = blockIdx.x * 256 + t; e < NE; e += gridDim.x * 256)
        atomicAdd(&lc[ei[NE + e] >> 8], 1);
    __syncthreads();
    if (lc[t]) atomicAdd(&bcnt[t], lc[t]);
}

__global__ __launch_bounds__(256) void k_bscan(
    const int* __restrict__ bcnt, int* __restrict__ ebase,
    int* __restrict__ cursor, int* __restrict__ rowreg)
{
    int t = threadIdx.x;
    int bc = (t < NB) ? bcnt[t] : 0;
    int nodes = (t < NB) ? min(256, NN - t * 256) : 0;
    int inc1 = block_scan_incl(bc, t);
    int eb = inc1 - bc;
    int inc2 = block_scan_incl(bc + nodes, t);
    int rr = inc2 - (bc + nodes);
    if (t < NB) { ebase[t] = eb; cursor[t] = eb; rowreg[t] = rr; }
}

__global__ __launch_bounds__(256) void k_bscatter(
    const int* __restrict__ ei, int* __restrict__ cursor,
    unsigned* __restrict__ pairbuf)
{
    __shared__ int lcnt[256], cstart[256], lcur[256], gpos[256];
    __shared__ unsigned sorted[CHUNK];
    __shared__ unsigned char sortedB[CHUNK];
    const int t = threadIdx.x;
    const int base = blockIdx.x * CHUNK;
    const int n = min(CHUNK, NE - base);
    if (n <= 0) return;

    lcnt[t] = 0;
    __syncthreads();

    unsigned pk[16];
    int bk[16];
#pragma unroll
    for (int i = 0; i < 16; i++) {
        int off = i * 256 + t;
        bk[i] = -1;
        if (off < n) {
            int e = base + off;
            int s = ei[e], d = ei[NE + e];
            bk[i] = d >> 8;
            pk[i] = ((unsigned)s << 8) | (unsigned)(d & 255);
            atomicAdd(&lcnt[bk[i]], 1);
        }
    }
    __syncthreads();

    int v = lcnt[t];
    int inc = block_scan_incl(v, t);
    cstart[t] = inc - v;
    lcur[t] = inc - v;
    __syncthreads();
    gpos[t] = (v > 0) ? atomicAdd(&cursor[t], v) : 0;
    __syncthreads();

#pragma unroll
    for (int i = 0; i < 16; i++) {
        if (bk[i] >= 0) {
            int r = atomicAdd(&lcur[bk[i]], 1);
            sorted[r] = pk[i];
            sortedB[r] = (unsigned char)bk[i];
        }
    }
    __syncthreads();

    for (int j = t; j < n; j += 256) {
        int b = sortedB[j];
        pairbuf[gpos[b] + (j - cstart[b])] = sorted[j];
    }
}

__global__ __launch_bounds__(256) void k_bbuild(
    const unsigned* __restrict__ pairbuf, const int* __restrict__ bcnt,
    const int* __restrict__ ebase, const int* __restrict__ rowreg,
    int* __restrict__ rowptr, int* __restrict__ esrc)
{
    __shared__ int ncnt[256], cur[256];
    const int b = blockIdx.x;
    const int t = threadIdx.x;
    const int node0 = b * 256;
    const int nnodes = min(256, NN - node0);
    const int cnt = bcnt[b];
    const int be = ebase[b];
    const int row0 = rowreg[b];

    ncnt[t] = 0;
    __syncthreads();
    for (int i = t; i < cnt; i += 256)
        atomicAdd(&ncnt[pairbuf[be + i] & 255u], 1);
    __syncthreads();

    int v = (t < nnodes) ? ncnt[t] + 1 : 0;  // +1 self-loop
    int inc = block_scan_incl(v, t);
    int rb = row0 + inc - v;
    if (t < nnodes) {
        rowptr[node0 + t] = rb;
        esrc[rb] = node0 + t;
        cur[t] = rb + 1;
    }
    if (b == NB - 1 && t == 0) rowptr[NN] = NE + NN;
    __syncthreads();

    for (int i = t; i < cnt; i += 256) {
        unsigned p = pairbuf[be + i];
        int pos = atomicAdd(&cur[p & 255u], 1);
        esrc[pos] = (int)(p >> 8);
    }
}

// ---------------------------------------------------------------------------
// GAT core: wave per dst node; four 16-lane groups, 4 edges/step.
// Packed-fp16 logit (pk_add/pk_mul/pk_max + dot2_f32_f16); f32 accumulate.
// ---------------------------------------------------------------------------
__device__ __forceinline__ void gat_core(
    const char* __restrict__ xlb, const int* __restrict__ esrc,
    int beg, int end, int lane, const uint4 xrq, const uint4 atq,
    float* acc, float& den)
{
    const int g = lane >> 4;
    const unsigned qb = (unsigned)((lane & 15) << 4);
#pragma unroll
    for (int i = 0; i < 8; i++) acc[i] = 0.f;
    den = 0.f;

    for (int sc = beg; sc < end; sc += 64) {
        const int nv = min(end - sc, 64);
        const int nit = (nv + 3) >> 2;
        int myidx = esrc[sc + min(lane, nv - 1)];

        auto LD = [&](int j) -> uint4 {
            int t = (j << 2) + g;
            int s = __shfl(myidx, min(t, nv - 1), 64);
            unsigned off = ((unsigned)s << 8) | qb;
            return *(const uint4*)(xlb + off);
        };

        uint4 A = LD(0);
        uint4 B = LD(nit > 1 ? 1 : 0);
        for (int jj = 0; jj < nit; ++jj) {
            uint4 C = LD(min(jj + 2, nit - 1));

            unsigned l0 = addleaky_h2(A.x, xrq.x);
            unsigned l1 = addleaky_h2(A.y, xrq.y);
            unsigned l2 = addleaky_h2(A.z, xrq.z);
            unsigned l3 = addleaky_h2(A.w, xrq.w);
            float e = fdot2f(l0, atq.x, 0.f);
            e = fdot2f(l1, atq.y, e);
            e = fdot2f(l2, atq.z, e);
            e = fdot2f(l3, atq.w, e);
#pragma unroll
            for (int off = 8; off; off >>= 1) e += __shfl_xor(e, off, 64);

            int t = (jj << 2) + g;
            float p = (t < nv) ? __expf(fminf(e, 80.f)) : 0.f;
            den += p;

            f32x2 x0 = cvt_h2(A.x), x1 = cvt_h2(A.y);
            f32x2 x2 = cvt_h2(A.z), x3 = cvt_h2(A.w);
            acc[0] = fmaf(p, x0[0], acc[0]);
            acc[1] = fmaf(p, x0[1], acc[1]);
            acc[2] = fmaf(p, x1[0], acc[2]);
            acc[3] = fmaf(p, x1[1], acc[3]);
            acc[4] = fmaf(p, x2[0], acc[4]);
            acc[5] = fmaf(p, x2[1], acc[5]);
            acc[6] = fmaf(p, x3[0], acc[6]);
            acc[7] = fmaf(p, x3[1], acc[7]);

            A = B; B = C;
        }
    }

#pragma unroll
    for (int off = 16; off < 64; off <<= 1) {
        den += __shfl_xor(den, off, 64);
#pragma unroll
        for (int i = 0; i < 8; i++) acc[i] += __shfl_xor(acc[i], off, 64);
    }
}

__device__ __forceinline__ uint4 ld_att_h2(const float* att, int q)
{
    float4 c = *(const float4*)(att + q * 8);
    float4 e = *(const float4*)(att + q * 8 + 4);
    __half2 t0 = __floats2half2_rn(c.x, c.y);
    __half2 t1 = __floats2half2_rn(c.z, c.w);
    __half2 t2 = __floats2half2_rn(e.x, e.y);
    __half2 t3 = __floats2half2_rn(e.z, e.w);
    uint4 r;
    r.x = *(unsigned*)&t0; r.y = *(unsigned*)&t1;
    r.z = *(unsigned*)&t2; r.w = *(unsigned*)&t3;
    return r;
}

// layer1: fused normalize + bias + ReLU + LayerNorm -> h16 (fp16)
__global__ __launch_bounds__(256, 6) void k_gat1(
    const char* __restrict__ xlb, const char* __restrict__ xrb,
    const float* __restrict__ att, const int* __restrict__ rowptr,
    const int* __restrict__ esrc, const float* __restrict__ bias,
    const float* __restrict__ g_ln, const float* __restrict__ b_ln,
    char* __restrict__ h16b)
{
    int d = (int)((blockIdx.x * 256 + threadIdx.x) >> 6);
    int lane = threadIdx.x & 63;
    if (d >= NN) return;
    int q = lane & 15;

    uint4 xrq = *(const uint4*)(xrb + ((size_t)d << 8) + (q << 4));
    uint4 atq = ld_att_h2(att, q);

    float acc[8]; float den;
    gat_core(xlb, esrc, rowptr[d], rowptr[d + 1], lane, xrq, atq, acc, den);

    float inv = 1.f / (den + 1e-16f);
    float x[8];
    {
        float4 a = *(const float4*)(bias + q * 8);
        float4 b = *(const float4*)(bias + q * 8 + 4);
        float bb[8] = {a.x,a.y,a.z,a.w,b.x,b.y,b.z,b.w};
#pragma unroll
        for (int i = 0; i < 8; i++) x[i] = fmaxf(fmaf(acc[i], inv, bb[i]), 0.f);
    }

    float s1 = 0.f, s2 = 0.f;
#pragma unroll
    for (int i = 0; i < 8; i++) { s1 += x[i]; s2 += x[i] * x[i]; }
#pragma unroll
    for (int off = 8; off; off >>= 1) {
        s1 += __shfl_xor(s1, off, 64);
        s2 += __shfl_xor(s2, off, 64);
    }
    float mu = s1 * (1.f / 128.f);
    float var = s2 * (1.f / 128.f) - mu * mu;
    float rstd = rsqrtf(var + 1e-5f);

    if (lane < 16) {
        float4 ga = *(const float4*)(g_ln + q * 8);
        float4 gb = *(const float4*)(g_ln + q * 8 + 4);
        float4 ba = *(const float4*)(b_ln + q * 8);
        float4 bb = *(const float4*)(b_ln + q * 8 + 4);
        float o[8];
        o[0] = (x[0]-mu)*rstd*ga.x + ba.x;
        o[1] = (x[1]-mu)*rstd*ga.y + ba.y;
        o[2] = (x[2]-mu)*rstd*ga.z + ba.z;
        o[3] = (x[3]-mu)*rstd*ga.w + ba.w;
        o[4] = (x[4]-mu)*rstd*gb.x + bb.x;
        o[5] = (x[5]-mu)*rstd*gb.y + bb.y;
        o[6] = (x[6]-mu)*rstd*gb.z + bb.z;
        o[7] = (x[7]-mu)*rstd*gb.w + bb.w;
        __half2 p0 = __floats2half2_rn(o[0], o[1]);
        __half2 p1 = __floats2half2_rn(o[2], o[3]);
        __half2 p2 = __floats2half2_rn(o[4], o[5]);
        __half2 p3 = __floats2half2_rn(o[6], o[7]);
        uint4 u;
        u.x = *(unsigned*)&p0; u.y = *(unsigned*)&p1;
        u.z = *(unsigned*)&p2; u.w = *(unsigned*)&p3;
        *(uint4*)(h16b + ((size_t)d << 8) + (q << 4)) = u;
    }
}

// layer2: fused normalize + bias -> h2h (fp16)
__global__ __launch_bounds__(256, 6) void k_gat2(
    const char* __restrict__ xlb, const char* __restrict__ xrb,
    const float* __restrict__ att, const int* __restrict__ rowptr,
    const int* __restrict__ esrc, const float* __restrict__ bias,
    char* __restrict__ h2b)
{
    int d = (int)((blockIdx.x * 256 + threadIdx.x) >> 6);
    int lane = threadIdx.x & 63;
    if (d >= NN) return;
    int q = lane & 15;

    uint4 xrq = *(const uint4*)(xrb + ((size_t)d << 8) + (q << 4));
    uint4 atq = ld_att_h2(att, q);

    float acc[8]; float den;
    gat_core(xlb, esrc, rowptr[d], rowptr[d + 1], lane, xrq, atq, acc, den);

    float inv = 1.f / (den + 1e-16f);
    if (lane < 16) {
        float4 a = *(const float4*)(bias + q * 8);
        float4 b = *(const float4*)(bias + q * 8 + 4);
        float o[8];
        o[0] = fmaf(acc[0], inv, a.x);
        o[1] = fmaf(acc[1], inv, a.y);
        o[2] = fmaf(acc[2], inv, a.z);
        o[3] = fmaf(acc[3], inv, a.w);
        o[4] = fmaf(acc[4], inv, b.x);
        o[5] = fmaf(acc[5], inv, b.y);
        o[6] = fmaf(acc[6], inv, b.z);
        o[7] = fmaf(acc[7], inv, b.w);
        __half2 p0 = __floats2half2_rn(o[0], o[1]);
        __half2 p1 = __floats2half2_rn(o[2], o[3]);
        __half2 p2 = __floats2half2_rn(o[4], o[5]);
        __half2 p3 = __floats2half2_rn(o[6], o[7]);
        uint4 u;
        u.x = *(unsigned*)&p0; u.y = *(unsigned*)&p1;
        u.z = *(unsigned*)&p2; u.w = *(unsigned*)&p3;
        *(uint4*)(h2b + ((size_t)d << 8) + (q << 4)) = u;
    }
}

// ---------------------------------------------------------------------------
#define NPB 100
__global__ __launch_bounds__(128) void k_pool(
    const __half* __restrict__ h2h, const int* __restrict__ batch,
    float* __restrict__ pooled, float* __restrict__ cnt)
{
    int n0 = blockIdx.x * NPB;
    int n1 = min(n0 + NPB, NN);
    if (n0 >= NN) return;
    int f = threadIdx.x;

    float s = 0.f;
    int c = 0;
    int curg = batch[n0];
    for (int n = n0; n < n1; n++) {
        int g = batch[n];
        if (g != curg) {
            atomicAdd(pooled + (size_t)curg * 128 + f, s);
            if (f == 0) atomicAdd(cnt + curg, (float)c);
            s = 0.f; c = 0; curg = g;
        }
        s += __half2float(h2h[(size_t)n * 128 + f]);
        c++;
    }
    atomicAdd(pooled + (size_t)curg * 128 + f, s);
    if (f == 0) atomicAdd(cnt + curg, (float)c);
}

// ---------------------------------------------------------------------------
__global__ __launch_bounds__(256) void k_linear(
    const float* __restrict__ pooled, const float* __restrict__ cnt,
    const float* __restrict__ W, const float* __restrict__ b,
    float* __restrict__ out)
{
    int idx = blockIdx.x * 256 + threadIdx.x;
    if (idx >= NG * NC) return;
    int g = idx / NC, c = idx % NC;
    float invc = 1.f / fmaxf(cnt[g], 1.f);
    float s = 0.f;
    for (int k = 0; k < HID; k++)
        s = fmaf(pooled[(size_t)g * 128 + k], W[(size_t)k * NC + c], s);
    out[idx] = fmaf(s, invc, b[c]);
}

// ---------------------------------------------------------------------------
extern "C" void kernel_launch(void* const* d_in, const int* in_sizes, int n_in,
                              void* d_out, int out_size, void* d_ws, size_t ws_size,
                              hipStream_t stream)
{
    const float* x     = (const float*)d_in[0];
    const int*   ei    = (const int*)d_in[1];
    const int*   batch = (const int*)d_in[2];
    const float* Wl1   = (const float*)d_in[3];
    const float* Wr1   = (const float*)d_in[4];
    const float* att1  = (const float*)d_in[5];
    const float* b1    = (const float*)d_in[6];
    const float* g_ln  = (const float*)d_in[7];
    const float* b_ln  = (const float*)d_in[8];
    const float* Wl2   = (const float*)d_in[9];
    const float* Wr2   = (const float*)d_in[10];
    const float* att2  = (const float*)d_in[11];
    const float* b2    = (const float*)d_in[12];
    const float* Wlin  = (const float*)d_in[13];
    const float* blin  = (const float*)d_in[14];
    float* out = (float*)d_out;

    char* ws = (char*)d_ws;
    __half* xlh16 = (__half*)ws;                          // 12.8 MB
    char*   xlb   = ws;
    __half* xrh16 = (__half*)(ws + (size_t)NN * 256);     // 12.8 MB
    char*   xrb   = (char*)xrh16;
    __half* h16   = xrh16 + (size_t)NN * 128;             // 12.8 MB
    char*   h16b  = (char*)h16;
    __half* h2h   = h16 + (size_t)NN * 128;               // 12.8 MB
    char*   h2b   = (char*)h2h;
    float* pooled = (float*)(h2h + (size_t)NN * 128);     // 128 KB
    float* cnt    = pooled + (size_t)NG * HID;            // 1 KB
    int* rowptr   = (int*)(cnt + NG);                     // NN+1
    int* esrc     = rowptr + NN + 1;                      // NE+NN
    unsigned* pairbuf = (unsigned*)(esrc + NE + NN);      // NE
    int* bcnt     = (int*)(pairbuf + NE);                 // 256
    int* ebase    = bcnt + 256;
    int* rowreg   = ebase + 256;
    int* cursor   = rowreg + 256;
    __half* wpk1  = (__half*)(cursor + 256);              // 64 KB
    __half* wpk2  = wpk1 + 32768;                         // 64 KB

    const int mg_blocks  = (NN + 63) / 64;
    const int gat_blocks = (NN * 64 + 255) / 256;
    const int sc_blocks  = (NE + CHUNK - 1) / CHUNK;

    // ---- W pack ----
    k_wpack<<<16, 256, 0, stream>>>(Wl1, Wr1, wpk1);
    k_wpack<<<16, 256, 0, stream>>>(Wl2, Wr2, wpk2);

    // ---- bucketed CSR build ----
    hipMemsetAsync(bcnt, 0, 256 * sizeof(int), stream);
    k_bcount<<<256, 256, 0, stream>>>(ei, bcnt);
    k_bscan<<<1, 256, 0, stream>>>(bcnt, ebase, cursor, rowreg);
    k_bscatter<<<sc_blocks, 256, 0, stream>>>(ei, cursor, pairbuf);
    k_bbuild<<<NB, 256, 0, stream>>>(pairbuf, bcnt, ebase, rowreg, rowptr, esrc);

    hipMemsetAsync(pooled, 0, ((size_t)NG * HID + NG) * sizeof(float), stream);

    // ---- layer 1 ----
    k_mgemm<true><<<mg_blocks, 256, 0, stream>>>(x, wpk1, xlh16, xrh16);
    k_gat1<<<gat_blocks, 256, 0, stream>>>(xlb, xrb, att1, rowptr, esrc,
                                           b1, g_ln, b_ln, h16b);

    // ---- layer 2 ----
    k_mgemm<false><<<mg_blocks, 256, 0, stream>>>(h16, wpk2, xlh16, xrh16);
    k_gat2<<<gat_blocks, 256, 0, stream>>>(xlb, xrb, att2, rowptr, esrc,
                                           b2, h2b);

    // ---- pool + head ----
    k_pool<<<(NN + NPB - 1) / NPB, 128, 0, stream>>>(h2h, batch, pooled, cnt);
    k_linear<<<(NG * NC + 255) / 256, 256, 0, stream>>>(pooled, cnt, Wlin, blin, out);
}

// Round 12
// 203.437 us; speedup vs baseline: 3.0155x; 1.0788x over previous
//
#include <hip/hip_runtime.h>
#include <hip/hip_bf16.h>
#include <hip/hip_fp16.h>

#define NN 50000
#define NE 800000
#define HID 128
#define NG 256
#define NC 10
#define NB 196    // buckets of 256 dst nodes
#define CHUNK 4096

using half8  = __attribute__((ext_vector_type(8))) _Float16;
using half2v = __attribute__((ext_vector_type(2))) _Float16;
using f32x4  = __attribute__((ext_vector_type(4))) float;

__device__ __forceinline__ float fdot2f(unsigned a, unsigned b, float c)
{
#if __has_builtin(__builtin_amdgcn_fdot2)
    return __builtin_amdgcn_fdot2(*(half2v*)&a, *(half2v*)&b, c, false);
#else
    float2 fa = __half22float2(*(__half2*)&a);
    float2 fb = __half22float2(*(__half2*)&b);
    return fmaf(fa.x, fb.x, fmaf(fa.y, fb.y, c));
#endif
}

// packed leaky_relu(xl + xr) in fp16: max(s, 0.2*s)
__device__ __forceinline__ unsigned addleaky_h2(unsigned xl, unsigned xr)
{
    half2v s = *(half2v*)&xl + *(half2v*)&xr;
    half2v l = __builtin_elementwise_max(s, s * (_Float16)0.2f);
    return *(unsigned*)&l;
}

// ---------------------------------------------------------------------------
// W pack (both layers) + zero pooled/cnt/bcnt.  grid = 32 x 256.
// Pack layout (per layer, R8): tile t in [0,16), kf in [0,4), lane in [0,64):
//   elem j = W[kf*32 + (lane>>4)*8 + j][ (t&7)*16 + (lane&15) ]
// ---------------------------------------------------------------------------
__global__ __launch_bounds__(256) void k_wpackz(
    const float* __restrict__ Wl1, const float* __restrict__ Wr1,
    const float* __restrict__ Wl2, const float* __restrict__ Wr2,
    __half* __restrict__ wpk1, __half* __restrict__ wpk2,
    float* __restrict__ pooled, float* __restrict__ cnt,
    int* __restrict__ bcnt)
{
    int gidx = blockIdx.x * 256 + threadIdx.x;    // 0..8191
#pragma unroll
    for (int i = 0; i < 4; i++) pooled[gidx + i * 8192] = 0.f;
    if (gidx < NG) cnt[gidx] = 0.f;
    else if (gidx < NG + 256) bcnt[gidx - NG] = 0;

    int idx = gidx & 4095;
    int layer = gidx >> 12;
    const float* Wl = layer ? Wl2 : Wl1;
    const float* Wr = layer ? Wr2 : Wr1;
    __half* wpk = layer ? wpk2 : wpk1;

    int t = idx >> 8;
    int lane = idx & 63;
    const float* W = (t < 8) ? Wl : Wr;
    int col = ((t & 7) << 4) + (lane & 15);
    int k0 = (((idx >> 6) & 3) << 5) + ((lane >> 4) << 3);
    __half tmp[8];
#pragma unroll
    for (int j = 0; j < 8; j++)
        tmp[j] = __float2half(W[(size_t)(k0 + j) * 128 + col]);
    *(uint4*)(wpk + ((size_t)idx << 3)) = *(uint4*)tmp;
}

// ---------------------------------------------------------------------------
// MFMA dual GEMM: xlh = fp16(in @ Wl), xrh = fp16(in @ Wr).
// ---------------------------------------------------------------------------
template <bool F32IN>
__global__ __launch_bounds__(256) void k_mgemm(
    const void* __restrict__ in, const __half* __restrict__ wpk,
    __half* __restrict__ xlh, __half* __restrict__ xrh)
{
    const int w = threadIdx.x >> 6;
    const int lane = threadIdx.x & 63;
    const int nodebase = blockIdx.x * 64 + w * 16;
    const int lrow = lane & 15;
    const int kb = lane >> 4;

    const int nload = min(nodebase + lrow, NN - 1);

    half8 a[4];
    if constexpr (F32IN) {
        const float* xp = (const float*)in + (size_t)nload * 128 + (kb << 3);
#pragma unroll
        for (int kf = 0; kf < 4; kf++) {
            float4 f0 = *(const float4*)(xp + kf * 32);
            float4 f1 = *(const float4*)(xp + kf * 32 + 4);
            half8 hh;
            hh[0] = (_Float16)f0.x; hh[1] = (_Float16)f0.y;
            hh[2] = (_Float16)f0.z; hh[3] = (_Float16)f0.w;
            hh[4] = (_Float16)f1.x; hh[5] = (_Float16)f1.y;
            hh[6] = (_Float16)f1.z; hh[7] = (_Float16)f1.w;
            a[kf] = hh;
        }
    } else {
        const char* xp = (const char*)in + (size_t)nload * 256 + (kb << 4);
#pragma unroll
        for (int kf = 0; kf < 4; kf++) {
            uint4 u = *(const uint4*)(xp + kf * 64);
            a[kf] = *(half8*)&u;
        }
    }

    const uint4* wp = (const uint4*)wpk + lane;

#pragma unroll
    for (int t = 0; t < 16; t++) {
        f32x4 acc = {0.f, 0.f, 0.f, 0.f};
#pragma unroll
        for (int kf = 0; kf < 4; kf++) {
            uint4 bu = wp[(t * 4 + kf) * 64];
            half8 b = *(half8*)&bu;
            acc = __builtin_amdgcn_mfma_f32_16x16x32_f16(a[kf], b, acc, 0, 0, 0);
        }
        int col = ((t & 7) << 4) + lrow;
#pragma unroll
        for (int i = 0; i < 4; i++) {
            int node = nodebase + kb * 4 + i;
            if (node < NN) {
                if (t < 8) xlh[(size_t)node * 128 + col] = __float2half(acc[i]);
                else       xrh[(size_t)node * 128 + col] = __float2half(acc[i]);
            }
        }
    }
}

// ---------------------------------------------------------------------------
// Bucketed CSR build.
// ---------------------------------------------------------------------------
__device__ __forceinline__ int block_scan_incl(int v, int t)
{
    __shared__ int sm[256];
    sm[t] = v;
    __syncthreads();
#pragma unroll
    for (int off = 1; off < 256; off <<= 1) {
        int u = (t >= off) ? sm[t - off] : 0;
        __syncthreads();
        sm[t] += u;
        __syncthreads();
    }
    return sm[t];
}

__global__ __launch_bounds__(256) void k_bcount(
    const int* __restrict__ ei, int* __restrict__ bcnt)
{
    __shared__ int lc[256];
    int t = threadIdx.x;
    lc[t] = 0;
    __syncthreads();
    for (int e = blockIdx.x * 256 + t; e < NE; e += gridDim.x * 256)
        atomicAdd(&lc[ei[NE + e] >> 8], 1);
    __syncthreads();
    if (lc[t]) atomicAdd(&bcnt[t], lc[t]);
}

__global__ __launch_bounds__(256) void k_bscan(
    const int* __restrict__ bcnt, int* __restrict__ ebase,
    int* __restrict__ cursor, int* __restrict__ rowreg)
{
    int t = threadIdx.x;
    int bc = (t < NB) ? bcnt[t] : 0;
    int nodes = (t < NB) ? min(256, NN - t * 256) : 0;
    int inc1 = block_scan_incl(bc, t);
    int eb = inc1 - bc;
    int inc2 = block_scan_incl(bc + nodes, t);
    int rr = inc2 - (bc + nodes);
    if (t < NB) { ebase[t] = eb; cursor[t] = eb; rowreg[t] = rr; }
}

__global__ __launch_bounds__(256) void k_bscatter(
    const int* __restrict__ ei, int* __restrict__ cursor,
    unsigned* __restrict__ pairbuf)
{
    __shared__ int lcnt[256], cstart[256], lcur[256], gpos[256];
    __shared__ unsigned sorted[CHUNK];
    __shared__ unsigned char sortedB[CHUNK];
    const int t = threadIdx.x;
    const int base = blockIdx.x * CHUNK;
    const int n = min(CHUNK, NE - base);
    if (n <= 0) return;

    lcnt[t] = 0;
    __syncthreads();

    unsigned pk[16];
    int bk[16];
#pragma unroll
    for (int i = 0; i < 16; i++) {
        int off = i * 256 + t;
        bk[i] = -1;
        if (off < n) {
            int e = base + off;
            int s = ei[e], d = ei[NE + e];
            bk[i] = d >> 8;
            pk[i] = ((unsigned)s << 8) | (unsigned)(d & 255);
            atomicAdd(&lcnt[bk[i]], 1);
        }
    }
    __syncthreads();

    int v = lcnt[t];
    int inc = block_scan_incl(v, t);
    cstart[t] = inc - v;
    lcur[t] = inc - v;
    __syncthreads();
    gpos[t] = (v > 0) ? atomicAdd(&cursor[t], v) : 0;
    __syncthreads();

#pragma unroll
    for (int i = 0; i < 16; i++) {
        if (bk[i] >= 0) {
            int r = atomicAdd(&lcur[bk[i]], 1);
            sorted[r] = pk[i];
            sortedB[r] = (unsigned char)bk[i];
        }
    }
    __syncthreads();

    for (int j = t; j < n; j += 256) {
        int b = sortedB[j];
        pairbuf[gpos[b] + (j - cstart[b])] = sorted[j];
    }
}

__global__ __launch_bounds__(256) void k_bbuild(
    const unsigned* __restrict__ pairbuf, const int* __restrict__ bcnt,
    const int* __restrict__ ebase, const int* __restrict__ rowreg,
    int* __restrict__ rowptr, int* __restrict__ esrc)
{
    __shared__ int ncnt[256], cur[256];
    const int b = blockIdx.x;
    const int t = threadIdx.x;
    const int node0 = b * 256;
    const int nnodes = min(256, NN - node0);
    const int cnt = bcnt[b];
    const int be = ebase[b];
    const int row0 = rowreg[b];

    ncnt[t] = 0;
    __syncthreads();
    for (int i = t; i < cnt; i += 256)
        atomicAdd(&ncnt[pairbuf[be + i] & 255u], 1);
    __syncthreads();

    int v = (t < nnodes) ? ncnt[t] + 1 : 0;  // +1 self-loop
    int inc = block_scan_incl(v, t);
    int rb = row0 + inc - v;
    if (t < nnodes) {
        rowptr[node0 + t] = rb;
        esrc[rb] = node0 + t;
        cur[t] = rb + 1;
    }
    if (b == NB - 1 && t == 0) rowptr[NN] = NE + NN;
    __syncthreads();

    for (int i = t; i < cnt; i += 256) {
        unsigned p = pairbuf[be + i];
        int pos = atomicAdd(&cur[p & 255u], 1);
        esrc[pos] = (int)(p >> 8);
    }
}

// ---------------------------------------------------------------------------
// GAT core: wave per dst node; four 16-lane groups, 4 edges/step.
// Full iterations carry no clamps/masks; single masked tail. Accumulate via
// fma with f16 source (v_fma_mix). Indices bounded once per chunk (&0xFFFF;
// over-reads land in adjacent allocated workspace).
// ---------------------------------------------------------------------------
#define GAT_LOGIT(A, e)                                                     \
    {                                                                       \
        unsigned l0 = addleaky_h2(A.x, xrq.x);                              \
        unsigned l1 = addleaky_h2(A.y, xrq.y);                              \
        unsigned l2 = addleaky_h2(A.z, xrq.z);                              \
        unsigned l3 = addleaky_h2(A.w, xrq.w);                              \
        e = fdot2f(l0, atq.x, 0.f);                                         \
        e = fdot2f(l1, atq.y, e);                                           \
        e = fdot2f(l2, atq.z, e);                                           \
        e = fdot2f(l3, atq.w, e);                                           \
        _Pragma("unroll")                                                   \
        for (int off = 8; off; off >>= 1) e += __shfl_xor(e, off, 64);      \
    }

#define GAT_ACC(A, p)                                                       \
    {                                                                       \
        half8 ah = *(half8*)&A;                                             \
        _Pragma("unroll")                                                   \
        for (int i = 0; i < 8; i++)                                         \
            acc[i] = fmaf(p, (float)ah[i], acc[i]);                         \
    }

__device__ __forceinline__ void gat_core(
    const char* __restrict__ xlb, const int* __restrict__ esrc,
    int beg, int end, int lane, const uint4 xrq, const uint4 atq,
    float* acc, float& den)
{
    const int g = lane >> 4;
    const unsigned qb = (unsigned)((lane & 15) << 4);
#pragma unroll
    for (int i = 0; i < 8; i++) acc[i] = 0.f;
    den = 0.f;

    for (int sc = beg; sc < end; sc += 64) {
        const int nv = min(end - sc, 64);
        const int nit = (nv + 3) >> 2;
        const int nfull = nv >> 2;
        int myidx = esrc[sc + lane] & 0xFFFF;   // bounded (garbage lanes safe)

        auto LD = [&](int j) -> uint4 {
            int t = (j << 2) + g;
            int s = __shfl(myidx, t, 64);
            unsigned off = ((unsigned)s << 8) | qb;
            return *(const uint4*)(xlb + off);
        };

        uint4 A = LD(0);
        uint4 B = LD(1 < nit ? 1 : 0);

        for (int jj = 0; jj < nfull; ++jj) {
            uint4 C = LD(jj + 2 < nit ? jj + 2 : nit - 1);
            float e;
            GAT_LOGIT(A, e)
            float p = __expf(fminf(e, 80.f));
            den += p;
            GAT_ACC(A, p)
            A = B; B = C;
        }
        if (nv & 3) {   // tail: A = LD(nfull)
            float e;
            GAT_LOGIT(A, e)
            float p = ((nfull << 2) + g < nv) ? __expf(fminf(e, 80.f)) : 0.f;
            den += p;
            GAT_ACC(A, p)
        }
    }

#pragma unroll
    for (int off = 16; off < 64; off <<= 1) {
        den += __shfl_xor(den, off, 64);
#pragma unroll
        for (int i = 0; i < 8; i++) acc[i] += __shfl_xor(acc[i], off, 64);
    }
}

__device__ __forceinline__ uint4 ld_att_h2(const float* att, int q)
{
    float4 c = *(const float4*)(att + q * 8);
    float4 e = *(const float4*)(att + q * 8 + 4);
    __half2 t0 = __floats2half2_rn(c.x, c.y);
    __half2 t1 = __floats2half2_rn(c.z, c.w);
    __half2 t2 = __floats2half2_rn(e.x, e.y);
    __half2 t3 = __floats2half2_rn(e.z, e.w);
    uint4 r;
    r.x = *(unsigned*)&t0; r.y = *(unsigned*)&t1;
    r.z = *(unsigned*)&t2; r.w = *(unsigned*)&t3;
    return r;
}

// layer1: fused normalize + bias + ReLU + LayerNorm -> h16 (fp16)
__global__ __launch_bounds__(256, 6) void k_gat1(
    const char* __restrict__ xlb, const char* __restrict__ xrb,
    const float* __restrict__ att, const int* __restrict__ rowptr,
    const int* __restrict__ esrc, const float* __restrict__ bias,
    const float* __restrict__ g_ln, const float* __restrict__ b_ln,
    char* __restrict__ h16b)
{
    int d = (int)((blockIdx.x * 256 + threadIdx.x) >> 6);
    int lane = threadIdx.x & 63;
    if (d >= NN) return;
    int q = lane & 15;

    uint4 xrq = *(const uint4*)(xrb + ((size_t)d << 8) + (q << 4));
    uint4 atq = ld_att_h2(att, q);

    float acc[8]; float den;
    gat_core(xlb, esrc, rowptr[d], rowptr[d + 1], lane, xrq, atq, acc, den);

    float inv = 1.f / (den + 1e-16f);
    float x[8];
    {
        float4 a = *(const float4*)(bias + q * 8);
        float4 b = *(const float4*)(bias + q * 8 + 4);
        float bb[8] = {a.x,a.y,a.z,a.w,b.x,b.y,b.z,b.w};
#pragma unroll
        for (int i = 0; i < 8; i++) x[i] = fmaxf(fmaf(acc[i], inv, bb[i]), 0.f);
    }

    float s1 = 0.f, s2 = 0.f;
#pragma unroll
    for (int i = 0; i < 8; i++) { s1 += x[i]; s2 += x[i] * x[i]; }
#pragma unroll
    for (int off = 8; off; off >>= 1) {
        s1 += __shfl_xor(s1, off, 64);
        s2 += __shfl_xor(s2, off, 64);
    }
    float mu = s1 * (1.f / 128.f);
    float var = s2 * (1.f / 128.f) - mu * mu;
    float rstd = rsqrtf(var + 1e-5f);

    if (lane < 16) {
        float4 ga = *(const float4*)(g_ln + q * 8);
        float4 gb = *(const float4*)(g_ln + q * 8 + 4);
        float4 ba = *(const float4*)(b_ln + q * 8);
        float4 bb = *(const float4*)(b_ln + q * 8 + 4);
        float o[8];
        o[0] = (x[0]-mu)*rstd*ga.x + ba.x;
        o[1] = (x[1]-mu)*rstd*ga.y + ba.y;
        o[2] = (x[2]-mu)*rstd*ga.z + ba.z;
        o[3] = (x[3]-mu)*rstd*ga.w + ba.w;
        o[4] = (x[4]-mu)*rstd*gb.x + bb.x;
        o[5] = (x[5]-mu)*rstd*gb.y + bb.y;
        o[6] = (x[6]-mu)*rstd*gb.z + bb.z;
        o[7] = (x[7]-mu)*rstd*gb.w + bb.w;
        __half2 p0 = __floats2half2_rn(o[0], o[1]);
        __half2 p1 = __floats2half2_rn(o[2], o[3]);
        __half2 p2 = __floats2half2_rn(o[4], o[5]);
        __half2 p3 = __floats2half2_rn(o[6], o[7]);
        uint4 u;
        u.x = *(unsigned*)&p0; u.y = *(unsigned*)&p1;
        u.z = *(unsigned*)&p2; u.w = *(unsigned*)&p3;
        *(uint4*)(h16b + ((size_t)d << 8) + (q << 4)) = u;
    }
}

// layer2: fused normalize + bias -> h2h (fp16)
__global__ __launch_bounds__(256, 6) void k_gat2(
    const char* __restrict__ xlb, const char* __restrict__ xrb,
    const float* __restrict__ att, const int* __restrict__ rowptr,
    const int* __restrict__ esrc, const float* __restrict__ bias,
    char* __restrict__ h2b)
{
    int d = (int)((blockIdx.x * 256 + threadIdx.x) >> 6);
    int lane = threadIdx.x & 63;
    if (d >= NN) return;
    int q = lane & 15;

    uint4 xrq = *(const uint4*)(xrb + ((size_t)d << 8) + (q << 4));
    uint4 atq = ld_att_h2(att, q);

    float acc[8]; float den;
    gat_core(xlb, esrc, rowptr[d], rowptr[d + 1], lane, xrq, atq, acc, den);

    float inv = 1.f / (den + 1e-16f);
    if (lane < 16) {
        float4 a = *(const float4*)(bias + q * 8);
        float4 b = *(const float4*)(bias + q * 8 + 4);
        float o[8];
        o[0] = fmaf(acc[0], inv, a.x);
        o[1] = fmaf(acc[1], inv, a.y);
        o[2] = fmaf(acc[2], inv, a.z);
        o[3] = fmaf(acc[3], inv, a.w);
        o[4] = fmaf(acc[4], inv, b.x);
        o[5] = fmaf(acc[5], inv, b.y);
        o[6] = fmaf(acc[6], inv, b.z);
        o[7] = fmaf(acc[7], inv, b.w);
        __half2 p0 = __floats2half2_rn(o[0], o[1]);
        __half2 p1 = __floats2half2_rn(o[2], o[3]);
        __half2 p2 = __floats2half2_rn(o[4], o[5]);
        __half2 p3 = __floats2half2_rn(o[6], o[7]);
        uint4 u;
        u.x = *(unsigned*)&p0; u.y = *(unsigned*)&p1;
        u.z = *(unsigned*)&p2; u.w = *(unsigned*)&p3;
        *(uint4*)(h2b + ((size_t)d << 8) + (q << 4)) = u;
    }
}

// ---------------------------------------------------------------------------
#define NPB 100
__global__ __launch_bounds__(128) void k_pool(
    const __half* __restrict__ h2h, const int* __restrict__ batch,
    float* __restrict__ pooled, float* __restrict__ cnt)
{
    int n0 = blockIdx.x * NPB;
    int n1 = min(n0 + NPB, NN);
    if (n0 >= NN) return;
    int f = threadIdx.x;

    float s = 0.f;
    int c = 0;
    int curg = batch[n0];
    for (int n = n0; n < n1; n++) {
        int g = batch[n];
        if (g != curg) {
            atomicAdd(pooled + (size_t)curg * 128 + f, s);
            if (f == 0) atomicAdd(cnt + curg, (float)c);
            s = 0.f; c = 0; curg = g;
        }
        s += __half2float(h2h[(size_t)n * 128 + f]);
        c++;
    }
    atomicAdd(pooled + (size_t)curg * 128 + f, s);
    if (f == 0) atomicAdd(cnt + curg, (float)c);
}

// ---------------------------------------------------------------------------
__global__ __launch_bounds__(256) void k_linear(
    const float* __restrict__ pooled, const float* __restrict__ cnt,
    const float* __restrict__ W, const float* __restrict__ b,
    float* __restrict__ out)
{
    int idx = blockIdx.x * 256 + threadIdx.x;
    if (idx >= NG * NC) return;
    int g = idx / NC, c = idx % NC;
    float invc = 1.f / fmaxf(cnt[g], 1.f);
    float s = 0.f;
    for (int k = 0; k < HID; k++)
        s = fmaf(pooled[(size_t)g * 128 + k], W[(size_t)k * NC + c], s);
    out[idx] = fmaf(s, invc, b[c]);
}

// ---------------------------------------------------------------------------
extern "C" void kernel_launch(void* const* d_in, const int* in_sizes, int n_in,
                              void* d_out, int out_size, void* d_ws, size_t ws_size,
                              hipStream_t stream)
{
    const float* x     = (const float*)d_in[0];
    const int*   ei    = (const int*)d_in[1];
    const int*   batch = (const int*)d_in[2];
    const float* Wl1   = (const float*)d_in[3];
    const float* Wr1   = (const float*)d_in[4];
    const float* att1  = (const float*)d_in[5];
    const float* b1    = (const float*)d_in[6];
    const float* g_ln  = (const float*)d_in[7];
    const float* b_ln  = (const float*)d_in[8];
    const float* Wl2   = (const float*)d_in[9];
    const float* Wr2   = (const float*)d_in[10];
    const float* att2  = (const float*)d_in[11];
    const float* b2    = (const float*)d_in[12];
    const float* Wlin  = (const float*)d_in[13];
    const float* blin  = (const float*)d_in[14];
    float* out = (float*)d_out;

    char* ws = (char*)d_ws;
    __half* xlh16 = (__half*)ws;                          // 12.8 MB
    char*   xlb   = ws;
    __half* xrh16 = (__half*)(ws + (size_t)NN * 256);     // 12.8 MB
    char*   xrb   = (char*)xrh16;
    __half* h16   = xrh16 + (size_t)NN * 128;             // 12.8 MB
    __half* h2h   = h16 + (size_t)NN * 128;               // 12.8 MB
    char*   h2b   = (char*)h2h;
    float* pooled = (float*)(h2h + (size_t)NN * 128);     // 128 KB
    float* cnt    = pooled + (size_t)NG * HID;            // 1 KB
    int* rowptr   = (int*)(cnt + NG);                     // NN+1
    int* esrc     = rowptr + NN + 1;                      // NE+NN
    unsigned* pairbuf = (unsigned*)(esrc + NE + NN);      // NE (also slack for esrc over-read)
    int* bcnt     = (int*)(pairbuf + NE);                 // 256
    int* ebase    = bcnt + 256;
    int* rowreg   = ebase + 256;
    int* cursor   = rowreg + 256;
    __half* wpk1  = (__half*)(cursor + 256);              // 64 KB
    __half* wpk2  = wpk1 + 32768;                         // 64 KB

    const int mg_blocks  = (NN + 63) / 64;
    const int gat_blocks = (NN * 64 + 255) / 256;
    const int sc_blocks  = (NE + CHUNK - 1) / CHUNK;

    // ---- W pack (both layers) + zero pooled/cnt/bcnt ----
    k_wpackz<<<32, 256, 0, stream>>>(Wl1, Wr1, Wl2, Wr2, wpk1, wpk2,
                                     pooled, cnt, bcnt);

    // ---- bucketed CSR build ----
    k_bcount<<<256, 256, 0, stream>>>(ei, bcnt);
    k_bscan<<<1, 256, 0, stream>>>(bcnt, ebase, cursor, rowreg);
    k_bscatter<<<sc_blocks, 256, 0, stream>>>(ei, cursor, pairbuf);
    k_bbuild<<<NB, 256, 0, stream>>>(pairbuf, bcnt, ebase, rowreg, rowptr, esrc);

    // ---- layer 1 ----
    k_mgemm<true><<<mg_blocks, 256, 0, stream>>>(x, wpk1, xlh16, xrh16);
    k_gat1<<<gat_blocks, 256, 0, stream>>>(xlb, xrb, att1, rowptr, esrc,
                                           b1, g_ln, b_ln, (char*)h16);

    // ---- layer 2 ----
    k_mgemm<false><<<mg_blocks, 256, 0, stream>>>(h16, wpk2, xlh16, xrh16);
    k_gat2<<<gat_blocks, 256, 0, stream>>>(xlb, xrb, att2, rowptr, esrc,
                                           b2, h2b);

    // ---- pool + head ----
    k_pool<<<(NN + NPB - 1) / NPB, 128, 0, stream>>>(h2h, batch, pooled, cnt);
    k_linear<<<(NG * NC + 255) / 256, 256, 0, stream>>>(pooled, cnt, Wlin, blin, out);
}

// Round 13
// 190.953 us; speedup vs baseline: 3.2127x; 1.0654x over previous
//
#include <hip/hip_runtime.h>
#include <hip/hip_bf16.h>
#include <hip/hip_fp16.h>

#define NN 50000
#define NE 800000
#define HID 128
#define NG 256
#define NC 10
#define NB 196    // buckets of 256 dst nodes
#define CHUNK 4096
#define BCAP 8192 // fixed pairbuf capacity per bucket (mean 4096, sigma 64)

using half8  = __attribute__((ext_vector_type(8))) _Float16;
using half2v = __attribute__((ext_vector_type(2))) _Float16;
using f32x4  = __attribute__((ext_vector_type(4))) float;

__device__ __forceinline__ float fdot2f(unsigned a, unsigned b, float c)
{
#if __has_builtin(__builtin_amdgcn_fdot2)
    return __builtin_amdgcn_fdot2(*(half2v*)&a, *(half2v*)&b, c, false);
#else
    float2 fa = __half22float2(*(__half2*)&a);
    float2 fb = __half22float2(*(__half2*)&b);
    return fmaf(fa.x, fb.x, fmaf(fa.y, fb.y, c));
#endif
}

// packed leaky_relu(xl + xr) in fp16: max(s, 0.2*s)
__device__ __forceinline__ unsigned addleaky_h2(unsigned xl, unsigned xr)
{
    half2v s = *(half2v*)&xl + *(half2v*)&xr;
    half2v l = __builtin_elementwise_max(s, s * (_Float16)0.2f);
    return *(unsigned*)&l;
}

// ---------------------------------------------------------------------------
// W pack (both layers) + zero pooled/cnt/cursor.  grid = 32 x 256.
// ---------------------------------------------------------------------------
__global__ __launch_bounds__(256) void k_wpackz(
    const float* __restrict__ Wl1, const float* __restrict__ Wr1,
    const float* __restrict__ Wl2, const float* __restrict__ Wr2,
    __half* __restrict__ wpk1, __half* __restrict__ wpk2,
    float* __restrict__ pooled, float* __restrict__ cnt,
    int* __restrict__ cursor)
{
    int gidx = blockIdx.x * 256 + threadIdx.x;    // 0..8191
#pragma unroll
    for (int i = 0; i < 4; i++) pooled[gidx + i * 8192] = 0.f;
    if (gidx < NG) cnt[gidx] = 0.f;
    else if (gidx < NG + 256) cursor[gidx - NG] = 0;

    int idx = gidx & 4095;
    int layer = gidx >> 12;
    const float* Wl = layer ? Wl2 : Wl1;
    const float* Wr = layer ? Wr2 : Wr1;
    __half* wpk = layer ? wpk2 : wpk1;

    int t = idx >> 8;
    int lane = idx & 63;
    const float* W = (t < 8) ? Wl : Wr;
    int col = ((t & 7) << 4) + (lane & 15);
    int k0 = (((idx >> 6) & 3) << 5) + ((lane >> 4) << 3);
    __half tmp[8];
#pragma unroll
    for (int j = 0; j < 8; j++)
        tmp[j] = __float2half(W[(size_t)(k0 + j) * 128 + col]);
    *(uint4*)(wpk + ((size_t)idx << 3)) = *(uint4*)tmp;
}

// ---------------------------------------------------------------------------
// MFMA dual GEMM: xlh = fp16(in @ Wl), xrh = fp16(in @ Wr).
// ---------------------------------------------------------------------------
template <bool F32IN>
__global__ __launch_bounds__(256) void k_mgemm(
    const void* __restrict__ in, const __half* __restrict__ wpk,
    __half* __restrict__ xlh, __half* __restrict__ xrh)
{
    const int w = threadIdx.x >> 6;
    const int lane = threadIdx.x & 63;
    const int nodebase = blockIdx.x * 64 + w * 16;
    const int lrow = lane & 15;
    const int kb = lane >> 4;

    const int nload = min(nodebase + lrow, NN - 1);

    half8 a[4];
    if constexpr (F32IN) {
        const float* xp = (const float*)in + (size_t)nload * 128 + (kb << 3);
#pragma unroll
        for (int kf = 0; kf < 4; kf++) {
            float4 f0 = *(const float4*)(xp + kf * 32);
            float4 f1 = *(const float4*)(xp + kf * 32 + 4);
            half8 hh;
            hh[0] = (_Float16)f0.x; hh[1] = (_Float16)f0.y;
            hh[2] = (_Float16)f0.z; hh[3] = (_Float16)f0.w;
            hh[4] = (_Float16)f1.x; hh[5] = (_Float16)f1.y;
            hh[6] = (_Float16)f1.z; hh[7] = (_Float16)f1.w;
            a[kf] = hh;
        }
    } else {
        const char* xp = (const char*)in + (size_t)nload * 256 + (kb << 4);
#pragma unroll
        for (int kf = 0; kf < 4; kf++) {
            uint4 u = *(const uint4*)(xp + kf * 64);
            a[kf] = *(half8*)&u;
        }
    }

    const uint4* wp = (const uint4*)wpk + lane;

#pragma unroll
    for (int t = 0; t < 16; t++) {
        f32x4 acc = {0.f, 0.f, 0.f, 0.f};
#pragma unroll
        for (int kf = 0; kf < 4; kf++) {
            uint4 bu = wp[(t * 4 + kf) * 64];
            half8 b = *(half8*)&bu;
            acc = __builtin_amdgcn_mfma_f32_16x16x32_f16(a[kf], b, acc, 0, 0, 0);
        }
        int col = ((t & 7) << 4) + lrow;
#pragma unroll
        for (int i = 0; i < 4; i++) {
            int node = nodebase + kb * 4 + i;
            if (node < NN) {
                if (t < 8) xlh[(size_t)node * 128 + col] = __float2half(acc[i]);
                else       xrh[(size_t)node * 128 + col] = __float2half(acc[i]);
            }
        }
    }
}

// ---------------------------------------------------------------------------
// Bucketed CSR build, 2 kernels. pairbuf slot b*BCAP; counts via cursor.
// pair = (src << 8) | (dst & 255)
// ---------------------------------------------------------------------------
__device__ __forceinline__ int block_scan_incl(int v, int t)
{
    __shared__ int sm[256];
    sm[t] = v;
    __syncthreads();
#pragma unroll
    for (int off = 1; off < 256; off <<= 1) {
        int u = (t >= off) ? sm[t - off] : 0;
        __syncthreads();
        sm[t] += u;
        __syncthreads();
    }
    return sm[t];
}

__global__ __launch_bounds__(256) void k_bscatter(
    const int* __restrict__ ei, int* __restrict__ cursor,
    unsigned* __restrict__ pairbuf)
{
    __shared__ int lcnt[256], cstart[256], lcur[256], gpos[256];
    __shared__ unsigned sorted[CHUNK];
    __shared__ unsigned char sortedB[CHUNK];
    const int t = threadIdx.x;
    const int base = blockIdx.x * CHUNK;
    const int n = min(CHUNK, NE - base);
    if (n <= 0) return;

    lcnt[t] = 0;
    __syncthreads();

    unsigned pk[16];
    int bk[16];
#pragma unroll
    for (int i = 0; i < 16; i++) {
        int off = i * 256 + t;
        bk[i] = -1;
        if (off < n) {
            int e = base + off;
            int s = ei[e], d = ei[NE + e];
            bk[i] = d >> 8;
            pk[i] = ((unsigned)s << 8) | (unsigned)(d & 255);
            atomicAdd(&lcnt[bk[i]], 1);
        }
    }
    __syncthreads();

    int v = lcnt[t];
    int inc = block_scan_incl(v, t);
    cstart[t] = inc - v;
    lcur[t] = inc - v;
    __syncthreads();
    gpos[t] = (v > 0) ? atomicAdd(&cursor[t], v) : 0;
    __syncthreads();

#pragma unroll
    for (int i = 0; i < 16; i++) {
        if (bk[i] >= 0) {
            int r = atomicAdd(&lcur[bk[i]], 1);
            sorted[r] = pk[i];
            sortedB[r] = (unsigned char)bk[i];
        }
    }
    __syncthreads();

    for (int j = t; j < n; j += 256) {
        int b = sortedB[j];
        pairbuf[(size_t)b * BCAP + gpos[b] + (j - cstart[b])] = sorted[j];
    }
}

// per-bucket: redundant 196-scan for row base; rowptr + self-loop + esrc.
__global__ __launch_bounds__(256) void k_bbuild(
    const unsigned* __restrict__ pairbuf, const int* __restrict__ cursor,
    int* __restrict__ rowptr, int* __restrict__ esrc)
{
    __shared__ int pre[256];
    __shared__ int ncnt[256], cur[256];
    const int b = blockIdx.x;
    const int t = threadIdx.x;
    const int node0 = b * 256;
    const int nnodes = min(256, NN - node0);

    // redundant prefix over (count + nodes) for all buckets
    int cb = (t < NB) ? cursor[t] : 0;
    int nodes = (t < NB) ? min(256, NN - t * 256) : 0;
    int inc = block_scan_incl(cb + nodes, t);
    pre[t] = inc;
    __syncthreads();
    const int row0 = (b == 0) ? 0 : pre[b - 1];
    const int cnt = cursor[b];
    const unsigned* pb = pairbuf + (size_t)b * BCAP;

    ncnt[t] = 0;
    __syncthreads();
    for (int i = t; i < cnt; i += 256)
        atomicAdd(&ncnt[pb[i] & 255u], 1);
    __syncthreads();

    int v = (t < nnodes) ? ncnt[t] + 1 : 0;  // +1 self-loop
    int inc2 = block_scan_incl(v, t);
    int rb = row0 + inc2 - v;
    if (t < nnodes) {
        rowptr[node0 + t] = rb;
        esrc[rb] = node0 + t;
        cur[t] = rb + 1;
    }
    if (b == NB - 1 && t == 0) rowptr[NN] = NE + NN;
    __syncthreads();

    for (int i = t; i < cnt; i += 256) {
        unsigned p = pb[i];
        int pos = atomicAdd(&cur[p & 255u], 1);
        esrc[pos] = (int)(p >> 8);
    }
}

// ---------------------------------------------------------------------------
// GAT core: wave per dst node; four 16-lane groups, 4 edges/step.
// ---------------------------------------------------------------------------
#define GAT_LOGIT(A, e)                                                     \
    {                                                                       \
        unsigned l0 = addleaky_h2(A.x, xrq.x);                              \
        unsigned l1 = addleaky_h2(A.y, xrq.y);                              \
        unsigned l2 = addleaky_h2(A.z, xrq.z);                              \
        unsigned l3 = addleaky_h2(A.w, xrq.w);                              \
        e = fdot2f(l0, atq.x, 0.f);                                         \
        e = fdot2f(l1, atq.y, e);                                           \
        e = fdot2f(l2, atq.z, e);                                           \
        e = fdot2f(l3, atq.w, e);                                           \
        _Pragma("unroll")                                                   \
        for (int off = 8; off; off >>= 1) e += __shfl_xor(e, off, 64);      \
    }

#define GAT_ACC(A, p)                                                       \
    {                                                                       \
        half8 ah = *(half8*)&A;                                             \
        _Pragma("unroll")                                                   \
        for (int i = 0; i < 8; i++)                                         \
            acc[i] = fmaf(p, (float)ah[i], acc[i]);                         \
    }

__device__ __forceinline__ void gat_core(
    const char* __restrict__ xlb, const int* __restrict__ esrc,
    int beg, int end, int lane, const uint4 xrq, const uint4 atq,
    float* acc, float& den)
{
    const int g = lane >> 4;
    const unsigned qb = (unsigned)((lane & 15) << 4);
#pragma unroll
    for (int i = 0; i < 8; i++) acc[i] = 0.f;
    den = 0.f;

    for (int sc = beg; sc < end; sc += 64) {
        const int nv = min(end - sc, 64);
        const int nit = (nv + 3) >> 2;
        const int nfull = nv >> 2;
        int myidx = esrc[sc + lane] & 0xFFFF;   // bounded (garbage lanes safe)

        auto LD = [&](int j) -> uint4 {
            int t = (j << 2) + g;
            int s = __shfl(myidx, t, 64);
            unsigned off = ((unsigned)s << 8) | qb;
            return *(const uint4*)(xlb + off);
        };

        uint4 A = LD(0);
        uint4 B = LD(1 < nit ? 1 : 0);

#pragma unroll 2
        for (int jj = 0; jj < nfull; ++jj) {
            uint4 C = LD(jj + 2 < nit ? jj + 2 : nit - 1);
            float e;
            GAT_LOGIT(A, e)
            float p = __expf(fminf(e, 80.f));
            den += p;
            GAT_ACC(A, p)
            A = B; B = C;
        }
        if (nv & 3) {   // tail: A = LD(nfull)
            float e;
            GAT_LOGIT(A, e)
            float p = ((nfull << 2) + g < nv) ? __expf(fminf(e, 80.f)) : 0.f;
            den += p;
            GAT_ACC(A, p)
        }
    }

#pragma unroll
    for (int off = 16; off < 64; off <<= 1) {
        den += __shfl_xor(den, off, 64);
#pragma unroll
        for (int i = 0; i < 8; i++) acc[i] += __shfl_xor(acc[i], off, 64);
    }
}

__device__ __forceinline__ uint4 ld_att_h2(const float* att, int q)
{
    float4 c = *(const float4*)(att + q * 8);
    float4 e = *(const float4*)(att + q * 8 + 4);
    __half2 t0 = __floats2half2_rn(c.x, c.y);
    __half2 t1 = __floats2half2_rn(c.z, c.w);
    __half2 t2 = __floats2half2_rn(e.x, e.y);
    __half2 t3 = __floats2half2_rn(e.z, e.w);
    uint4 r;
    r.x = *(unsigned*)&t0; r.y = *(unsigned*)&t1;
    r.z = *(unsigned*)&t2; r.w = *(unsigned*)&t3;
    return r;
}

// layer1: fused normalize + bias + ReLU + LayerNorm -> h16 (fp16)
__global__ __launch_bounds__(256, 8) void k_gat1(
    const char* __restrict__ xlb, const char* __restrict__ xrb,
    const float* __restrict__ att, const int* __restrict__ rowptr,
    const int* __restrict__ esrc, const float* __restrict__ bias,
    const float* __restrict__ g_ln, const float* __restrict__ b_ln,
    char* __restrict__ h16b)
{
    int d = (int)((blockIdx.x * 256 + threadIdx.x) >> 6);  // grid exact
    int lane = threadIdx.x & 63;
    int q = lane & 15;

    uint4 xrq = *(const uint4*)(xrb + ((size_t)d << 8) + (q << 4));
    uint4 atq = ld_att_h2(att, q);

    float acc[8]; float den;
    gat_core(xlb, esrc, rowptr[d], rowptr[d + 1], lane, xrq, atq, acc, den);

    float inv = 1.f / (den + 1e-16f);
    float x[8];
    {
        float4 a = *(const float4*)(bias + q * 8);
        float4 b = *(const float4*)(bias + q * 8 + 4);
        float bb[8] = {a.x,a.y,a.z,a.w,b.x,b.y,b.z,b.w};
#pragma unroll
        for (int i = 0; i < 8; i++) x[i] = fmaxf(fmaf(acc[i], inv, bb[i]), 0.f);
    }

    float s1 = 0.f, s2 = 0.f;
#pragma unroll
    for (int i = 0; i < 8; i++) { s1 += x[i]; s2 += x[i] * x[i]; }
#pragma unroll
    for (int off = 8; off; off >>= 1) {
        s1 += __shfl_xor(s1, off, 64);
        s2 += __shfl_xor(s2, off, 64);
    }
    float mu = s1 * (1.f / 128.f);
    float var = s2 * (1.f / 128.f) - mu * mu;
    float rstd = rsqrtf(var + 1e-5f);

    if (lane < 16) {
        float4 ga = *(const float4*)(g_ln + q * 8);
        float4 gb = *(const float4*)(g_ln + q * 8 + 4);
        float4 ba = *(const float4*)(b_ln + q * 8);
        float4 bb = *(const float4*)(b_ln + q * 8 + 4);
        float o[8];
        o[0] = (x[0]-mu)*rstd*ga.x + ba.x;
        o[1] = (x[1]-mu)*rstd*ga.y + ba.y;
        o[2] = (x[2]-mu)*rstd*ga.z + ba.z;
        o[3] = (x[3]-mu)*rstd*ga.w + ba.w;
        o[4] = (x[4]-mu)*rstd*gb.x + bb.x;
        o[5] = (x[5]-mu)*rstd*gb.y + bb.y;
        o[6] = (x[6]-mu)*rstd*gb.z + bb.z;
        o[7] = (x[7]-mu)*rstd*gb.w + bb.w;
        __half2 p0 = __floats2half2_rn(o[0], o[1]);
        __half2 p1 = __floats2half2_rn(o[2], o[3]);
        __half2 p2 = __floats2half2_rn(o[4], o[5]);
        __half2 p3 = __floats2half2_rn(o[6], o[7]);
        uint4 u;
        u.x = *(unsigned*)&p0; u.y = *(unsigned*)&p1;
        u.z = *(unsigned*)&p2; u.w = *(unsigned*)&p3;
        *(uint4*)(h16b + ((size_t)d << 8) + (q << 4)) = u;
    }
}

// layer2: fused normalize + bias -> h2h (fp16)
__global__ __launch_bounds__(256, 8) void k_gat2(
    const char* __restrict__ xlb, const char* __restrict__ xrb,
    const float* __restrict__ att, const int* __restrict__ rowptr,
    const int* __restrict__ esrc, const float* __restrict__ bias,
    char* __restrict__ h2b)
{
    int d = (int)((blockIdx.x * 256 + threadIdx.x) >> 6);
    int lane = threadIdx.x & 63;
    int q = lane & 15;

    uint4 xrq = *(const uint4*)(xrb + ((size_t)d << 8) + (q << 4));
    uint4 atq = ld_att_h2(att, q);

    float acc[8]; float den;
    gat_core(xlb, esrc, rowptr[d], rowptr[d + 1], lane, xrq, atq, acc, den);

    float inv = 1.f / (den + 1e-16f);
    if (lane < 16) {
        float4 a = *(const float4*)(bias + q * 8);
        float4 b = *(const float4*)(bias + q * 8 + 4);
        float o[8];
        o[0] = fmaf(acc[0], inv, a.x);
        o[1] = fmaf(acc[1], inv, a.y);
        o[2] = fmaf(acc[2], inv, a.z);
        o[3] = fmaf(acc[3], inv, a.w);
        o[4] = fmaf(acc[4], inv, b.x);
        o[5] = fmaf(acc[5], inv, b.y);
        o[6] = fmaf(acc[6], inv, b.z);
        o[7] = fmaf(acc[7], inv, b.w);
        __half2 p0 = __floats2half2_rn(o[0], o[1]);
        __half2 p1 = __floats2half2_rn(o[2], o[3]);
        __half2 p2 = __floats2half2_rn(o[4], o[5]);
        __half2 p3 = __floats2half2_rn(o[6], o[7]);
        uint4 u;
        u.x = *(unsigned*)&p0; u.y = *(unsigned*)&p1;
        u.z = *(unsigned*)&p2; u.w = *(unsigned*)&p3;
        *(uint4*)(h2b + ((size_t)d << 8) + (q << 4)) = u;
    }
}

// ---------------------------------------------------------------------------
#define NPB 100
__global__ __launch_bounds__(128) void k_pool(
    const __half* __restrict__ h2h, const int* __restrict__ batch,
    float* __restrict__ pooled, float* __restrict__ cnt)
{
    int n0 = blockIdx.x * NPB;
    int n1 = min(n0 + NPB, NN);
    if (n0 >= NN) return;
    int f = threadIdx.x;

    float s = 0.f;
    int c = 0;
    int curg = batch[n0];
    for (int n = n0; n < n1; n++) {
        int g = batch[n];
        if (g != curg) {
            atomicAdd(pooled + (size_t)curg * 128 + f, s);
            if (f == 0) atomicAdd(cnt + curg, (float)c);
            s = 0.f; c = 0; curg = g;
        }
        s += __half2float(h2h[(size_t)n * 128 + f]);
        c++;
    }
    atomicAdd(pooled + (size_t)curg * 128 + f, s);
    if (f == 0) atomicAdd(cnt + curg, (float)c);
}

// ---------------------------------------------------------------------------
__global__ __launch_bounds__(256) void k_linear(
    const float* __restrict__ pooled, const float* __restrict__ cnt,
    const float* __restrict__ W, const float* __restrict__ b,
    float* __restrict__ out)
{
    int idx = blockIdx.x * 256 + threadIdx.x;
    if (idx >= NG * NC) return;
    int g = idx / NC, c = idx % NC;
    float invc = 1.f / fmaxf(cnt[g], 1.f);
    float s = 0.f;
    for (int k = 0; k < HID; k++)
        s = fmaf(pooled[(size_t)g * 128 + k], W[(size_t)k * NC + c], s);
    out[idx] = fmaf(s, invc, b[c]);
}

// ---------------------------------------------------------------------------
extern "C" void kernel_launch(void* const* d_in, const int* in_sizes, int n_in,
                              void* d_out, int out_size, void* d_ws, size_t ws_size,
                              hipStream_t stream)
{
    const float* x     = (const float*)d_in[0];
    const int*   ei    = (const int*)d_in[1];
    const int*   batch = (const int*)d_in[2];
    const float* Wl1   = (const float*)d_in[3];
    const float* Wr1   = (const float*)d_in[4];
    const float* att1  = (const float*)d_in[5];
    const float* b1    = (const float*)d_in[6];
    const float* g_ln  = (const float*)d_in[7];
    const float* b_ln  = (const float*)d_in[8];
    const float* Wl2   = (const float*)d_in[9];
    const float* Wr2   = (const float*)d_in[10];
    const float* att2  = (const float*)d_in[11];
    const float* b2    = (const float*)d_in[12];
    const float* Wlin  = (const float*)d_in[13];
    const float* blin  = (const float*)d_in[14];
    float* out = (float*)d_out;

    char* ws = (char*)d_ws;
    __half* xlh16 = (__half*)ws;                          // 12.8 MB
    char*   xlb   = ws;
    __half* xrh16 = (__half*)(ws + (size_t)NN * 256);     // 12.8 MB
    char*   xrb   = (char*)xrh16;
    __half* h16   = xrh16 + (size_t)NN * 128;             // 12.8 MB
    __half* h2h   = h16 + (size_t)NN * 128;               // 12.8 MB
    char*   h2b   = (char*)h2h;
    float* pooled = (float*)(h2h + (size_t)NN * 128);     // 128 KB
    float* cnt    = pooled + (size_t)NG * HID;            // 1 KB
    int* rowptr   = (int*)(cnt + NG);                     // NN+1
    int* esrc     = rowptr + NN + 1;                      // NE+NN
    unsigned* pairbuf = (unsigned*)(esrc + NE + NN);      // NB*BCAP = 6.4 MB
    int* cursor   = (int*)(pairbuf + (size_t)NB * BCAP);  // 256
    __half* wpk1  = (__half*)(cursor + 256);              // 64 KB
    __half* wpk2  = wpk1 + 32768;                         // 64 KB

    const int mg_blocks  = (NN + 63) / 64;
    const int gat_blocks = (NN * 64) / 256;               // exact: 12500
    const int sc_blocks  = (NE + CHUNK - 1) / CHUNK;

    // ---- W pack (both layers) + zero pooled/cnt/cursor ----
    k_wpackz<<<32, 256, 0, stream>>>(Wl1, Wr1, Wl2, Wr2, wpk1, wpk2,
                                     pooled, cnt, cursor);

    // ---- bucketed CSR build (2 kernels) ----
    k_bscatter<<<sc_blocks, 256, 0, stream>>>(ei, cursor, pairbuf);
    k_bbuild<<<NB, 256, 0, stream>>>(pairbuf, cursor, rowptr, esrc);

    // ---- layer 1 ----
    k_mgemm<true><<<mg_blocks, 256, 0, stream>>>(x, wpk1, xlh16, xrh16);
    k_gat1<<<gat_blocks, 256, 0, stream>>>(xlb, xrb, att1, rowptr, esrc,
                                           b1, g_ln, b_ln, (char*)h16);

    // ---- layer 2 ----
    k_mgemm<false><<<mg_blocks, 256, 0, stream>>>(h16, wpk2, xlh16, xrh16);
    k_gat2<<<gat_blocks, 256, 0, stream>>>(xlb, xrb, att2, rowptr, esrc,
                                           b2, h2b);

    // ---- pool + head ----
    k_pool<<<(NN + NPB - 1) / NPB, 128, 0, stream>>>(h2h, batch, pooled, cnt);
    k_linear<<<(NG * NC + 255) / 256, 256, 0, stream>>>(pooled, cnt, Wlin, blin, out);
}